// Round 1
// baseline (6249.092 us; speedup 1.0000x reference)
//
#include <hip/hip_runtime.h>
#include <math.h>

// ---- problem constants ----
constexpr int BSZ = 2;            // batch
constexpr int CH  = 256;          // d_model
constexpr int IH  = 96, IW = 96;  // input H, W
constexpr int HSS = 24, WSS = 24; // aggregated H, W
constexpr int SL  = HSS * WSS;    // 576 tokens
constexpr int NHD = 8, DHD = 32;  // heads, head dim
constexpr int CH2 = 512;          // 2*d_model
constexpr int PIX = IH * IW;      // 9216
constexpr int MATT = BSZ * SL;    // 1152
constexpr int MFFN = BSZ * PIX;   // 18432
constexpr long FEATN = (long)BSZ * PIX * CH;  // 4,718,592 elements per feature

// ---------------- block reductions ----------------
__device__ inline float blockSum(float v, float* red) {
  int t = threadIdx.x;
  red[t] = v; __syncthreads();
  for (int s = 128; s > 0; s >>= 1) {
    if (t < s) red[t] += red[t + s];
    __syncthreads();
  }
  float r = red[0]; __syncthreads();
  return r;
}
__device__ inline float blockMax(float v, float* red) {
  int t = threadIdx.x;
  red[t] = v; __syncthreads();
  for (int s = 128; s > 0; s >>= 1) {
    if (t < s) red[t] = fmaxf(red[t], red[t + s]);
    __syncthreads();
  }
  float r = red[0]; __syncthreads();
  return r;
}

// ---------------- layout transforms ----------------
__global__ __launch_bounds__(256) void k_nchw2nhwc(const float* __restrict__ in,
                                                   float* __restrict__ out) {
  long idx = (long)blockIdx.x * 256 + threadIdx.x;  // over FEATN, c fastest
  int  c    = (int)(idx & (CH - 1));
  long rest = idx >> 8;            // b*PIX + p
  long p    = rest % PIX;
  long b    = rest / PIX;
  out[idx] = in[(b * CH + c) * PIX + p];
}

__global__ __launch_bounds__(256) void k_nhwc2nchw(const float* __restrict__ in,
                                                   float* __restrict__ out) {
  long idx = (long)blockIdx.x * 256 + threadIdx.x;  // over FEATN, p fastest
  long p    = idx % PIX;
  long rest = idx / PIX;
  int  c    = (int)(rest % CH);
  long b    = rest / CH;
  out[idx] = in[(b * PIX + p) * CH + c];
}

__global__ __launch_bounds__(256) void k_copy(const float* __restrict__ in,
                                              float* __restrict__ out) {
  long idx = (long)blockIdx.x * 256 + threadIdx.x;
  out[idx] = in[idx];
}

// ---------------- RoPE tables (same for all layers; 24x24 grid) ----------------
__global__ __launch_bounds__(256) void k_rope_tables(float* __restrict__ sinT,
                                                     float* __restrict__ cosT) {
  int l = blockIdx.x;      // 0..575
  int d = threadIdx.x;     // 0..255
  int ii = l / WSS + 1;
  int jj = l % WSS + 1;
  int kidx = d >> 2;                       // 0..63
  bool is_i = ((d >> 1) & 1) == 0;
  float div = expf((float)kidx * -0.14391156831212787f);  // -ln(10000)/64
  float pos = is_i ? (float)ii : (float)jj;
  float ang = pos * div;
  sinT[(long)l * CH + d] = sinf(ang);
  cosT[(long)l * CH + d] = cosf(ang);
}

// ---------------- aggregation: depthwise conv (q) / maxpool (s) + LayerNorm ----------------
__global__ __launch_bounds__(256) void k_agg(const float* __restrict__ x,
                                             const float* __restrict__ src,
                                             const float* __restrict__ aggw,
                                             const float* __restrict__ g,
                                             const float* __restrict__ bt,
                                             float* __restrict__ qln,
                                             float* __restrict__ sln) {
  int bi = blockIdx.x;
  int mode = 0;
  if (bi >= BSZ * SL) { mode = 1; bi -= BSZ * SL; }
  int b = bi / SL, l = bi % SL;
  int i = l / WSS, j = l % WSS;
  int c = threadIdx.x;
  const float* in = mode ? src : x;   // NHWC
  float v;
  if (mode == 0) {
    v = 0.f;
#pragma unroll
    for (int r = 0; r < 4; ++r)
#pragma unroll
      for (int s = 0; s < 4; ++s)
        v += in[(((long)b * IH + i * 4 + r) * IW + j * 4 + s) * CH + c] *
             aggw[c * 16 + r * 4 + s];
  } else {
    v = -INFINITY;
#pragma unroll
    for (int r = 0; r < 4; ++r)
#pragma unroll
      for (int s = 0; s < 4; ++s)
        v = fmaxf(v, in[(((long)b * IH + i * 4 + r) * IW + j * 4 + s) * CH + c]);
  }
  __shared__ float red[256];
  float mu = blockSum(v, red) * (1.f / CH);
  float dv = v - mu;
  float var = blockSum(dv * dv, red) * (1.f / CH);
  float o = dv * rsqrtf(var + 1e-5f) * g[c] + bt[c];
  (mode ? sln : qln)[(long)(b * SL + l) * CH + c] = o;
}

// ---------------- generic f32 GEMM: C[M,N] = A[M,K] @ B[K,N] ----------------
// EPI: 0 = none, 1 = LeakyReLU(0.01), 2 = RoPE epilogue (tables indexed by row%SL, col)
template <int EPI>
__global__ __launch_bounds__(256) void k_gemm(const float* __restrict__ A,
                                              const float* __restrict__ Bw,
                                              float* __restrict__ Cc,
                                              int M, int N, int K,
                                              const float* __restrict__ sinT,
                                              const float* __restrict__ cosT) {
  __shared__ float As[16][68];
  __shared__ float Bsh[16][68];
  const int bm = blockIdx.x * 64, bn = blockIdx.y * 64;
  const int tid = threadIdx.x;
  const int tx = tid & 15, ty = tid >> 4;
  float acc[4][4] = {};
  for (int k0 = 0; k0 < K; k0 += 16) {
#pragma unroll
    for (int i = 0; i < 4; ++i) {
      int idx = tid + i * 256;
      As[idx & 15][idx >> 4] = A[(long)(bm + (idx >> 4)) * K + k0 + (idx & 15)];
      Bsh[idx >> 6][idx & 63] = Bw[(long)(k0 + (idx >> 6)) * N + bn + (idx & 63)];
    }
    __syncthreads();
#pragma unroll
    for (int kk = 0; kk < 16; ++kk) {
      float a[4], b[4];
#pragma unroll
      for (int i = 0; i < 4; ++i) a[i] = As[kk][ty * 4 + i];
#pragma unroll
      for (int j = 0; j < 4; ++j) b[j] = Bsh[kk][tx * 4 + j];
#pragma unroll
      for (int i = 0; i < 4; ++i)
#pragma unroll
        for (int j = 0; j < 4; ++j) acc[i][j] += a[i] * b[j];
    }
    __syncthreads();
  }
#pragma unroll
  for (int i = 0; i < 4; ++i) {
    int row = bm + ty * 4 + i;
    int col = bn + tx * 4;
    float o0 = acc[i][0], o1 = acc[i][1], o2 = acc[i][2], o3 = acc[i][3];
    if (EPI == 1) {
      o0 = o0 >= 0.f ? o0 : 0.01f * o0;
      o1 = o1 >= 0.f ? o1 : 0.01f * o1;
      o2 = o2 >= 0.f ? o2 : 0.01f * o2;
      o3 = o3 >= 0.f ? o3 : 0.01f * o3;
    } else if (EPI == 2) {
      int l = row % SL;
      const float* sr = sinT + (long)l * CH + col;
      const float* cr = cosT + (long)l * CH + col;
      float n0 = o0 * cr[0] - o1 * sr[0];
      float n1 = o1 * cr[1] + o0 * sr[1];
      float n2 = o2 * cr[2] - o3 * sr[2];
      float n3 = o3 * cr[3] + o2 * sr[3];
      o0 = n0; o1 = n1; o2 = n2; o3 = n3;
    }
    float4 ov = make_float4(o0, o1, o2, o3);
    *reinterpret_cast<float4*>(&Cc[(long)row * N + col]) = ov;
  }
}

// ---------------- attention scores: sc[bh, l, s] = q·k / sqrt(dh) ----------------
__global__ __launch_bounds__(256) void k_scores(const float* __restrict__ q,
                                                const float* __restrict__ k,
                                                float* __restrict__ sc) {
  const int bh = blockIdx.x;
  const int b = bh >> 3, h = bh & 7;
  const int mB = blockIdx.y * 64, nB = blockIdx.z * 64;
  __shared__ float Qs[64][33];
  __shared__ float Ks[64][33];
  const int tid = threadIdx.x;
#pragma unroll
  for (int i = 0; i < 8; ++i) {
    int idx = tid + i * 256;
    int d = idx & 31, r = idx >> 5;
    Qs[r][d] = q[(long)(b * SL + mB + r) * CH + h * DHD + d];
    Ks[r][d] = k[(long)(b * SL + nB + r) * CH + h * DHD + d];
  }
  __syncthreads();
  const int tx = tid & 15, ty = tid >> 4;
  float acc[4][4] = {};
#pragma unroll
  for (int kk = 0; kk < 32; ++kk) {
    float a[4], bb[4];
#pragma unroll
    for (int i = 0; i < 4; ++i) a[i] = Qs[ty * 4 + i][kk];
#pragma unroll
    for (int j = 0; j < 4; ++j) bb[j] = Ks[tx * 4 + j][kk];
#pragma unroll
    for (int i = 0; i < 4; ++i)
#pragma unroll
      for (int j = 0; j < 4; ++j) acc[i][j] += a[i] * bb[j];
  }
  const float scale = 0.17677669529663687f;  // 1/sqrt(32)
#pragma unroll
  for (int i = 0; i < 4; ++i) {
    long row = (long)bh * SL + mB + ty * 4 + i;
    float4 ov = make_float4(acc[i][0] * scale, acc[i][1] * scale,
                            acc[i][2] * scale, acc[i][3] * scale);
    *reinterpret_cast<float4*>(&sc[row * SL + nB + tx * 4]) = ov;
  }
}

// ---------------- row softmax over S=576 ----------------
__global__ __launch_bounds__(256) void k_softmax(float* __restrict__ sc) {
  __shared__ float red[256];
  long row = blockIdx.x;
  float* p = sc + row * SL;
  int t = threadIdx.x;
  float mx = -1e30f;
  for (int i = t; i < SL; i += 256) mx = fmaxf(mx, p[i]);
  float m = blockMax(mx, red);
  float s = 0.f;
  for (int i = t; i < SL; i += 256) {
    float e = expf(p[i] - m);
    p[i] = e;
    s += e;
  }
  float tot = blockSum(s, red);
  float inv = 1.f / tot;
  for (int i = t; i < SL; i += 256) p[i] *= inv;
}

// ---------------- attn @ V -> msg[b, l, h*32+d] ----------------
__global__ __launch_bounds__(256) void k_attnv(const float* __restrict__ att,
                                               const float* __restrict__ v,
                                               float* __restrict__ out) {
  const int bh = blockIdx.x;
  const int b = bh >> 3, h = bh & 7;
  const int mB = blockIdx.y * 64;
  const int tid = threadIdx.x;
  const int d = tid & 31, q8 = tid >> 5;
  __shared__ float As[64][65];
  __shared__ float Vs[64][33];
  float acc[8] = {};
  for (int s0 = 0; s0 < SL; s0 += 64) {
#pragma unroll
    for (int i = 0; i < 16; ++i) {
      int idx = tid + i * 256;
      int cc = idx & 63, r = idx >> 6;
      As[r][cc] = att[((long)bh * SL + mB + r) * SL + s0 + cc];
    }
#pragma unroll
    for (int i = 0; i < 8; ++i) {
      int idx = tid + i * 256;
      int dd = idx & 31, r = idx >> 5;
      Vs[r][dd] = v[(long)(b * SL + s0 + r) * CH + h * DHD + dd];
    }
    __syncthreads();
#pragma unroll
    for (int r = 0; r < 8; ++r) {
      int lr = q8 * 8 + r;
      float a = 0.f;
#pragma unroll
      for (int ss = 0; ss < 64; ++ss) a += As[lr][ss] * Vs[ss][d];
      acc[r] += a;
    }
    __syncthreads();
  }
#pragma unroll
  for (int r = 0; r < 8; ++r)
    out[(long)(b * SL + mB + q8 * 8 + r) * CH + h * DHD + d] = acc[r];
}

// ---------------- bilinear upsample x4 + concat [x, up] -> cat[pix, 512] ----------------
__global__ __launch_bounds__(256) void k_cat(const float* __restrict__ xf,
                                             const float* __restrict__ m2,
                                             float* __restrict__ cat) {
  int pb = blockIdx.x;                 // b*PIX + p
  int b = pb / PIX, p = pb % PIX;
  int y = p / IW, xx = p % IW;
  int c = threadIdx.x;
  float xv = xf[(long)pb * CH + c];
  float sy = (y + 0.5f) * 0.25f - 0.5f;
  float sx = (xx + 0.5f) * 0.25f - 0.5f;
  int y0 = (int)floorf(sy); float wy = sy - y0;
  int x0 = (int)floorf(sx); float wx = sx - x0;
  int y1 = min(y0 + 1, HSS - 1); y0 = max(y0, 0);
  int x1 = min(x0 + 1, WSS - 1); x0 = max(x0, 0);
  const float* mb = m2 + (long)b * SL * CH;
  float v00 = mb[(y0 * WSS + x0) * CH + c];
  float v01 = mb[(y0 * WSS + x1) * CH + c];
  float v10 = mb[(y1 * WSS + x0) * CH + c];
  float v11 = mb[(y1 * WSS + x1) * CH + c];
  float up = (1.f - wy) * ((1.f - wx) * v00 + wx * v01) +
             wy * ((1.f - wx) * v10 + wx * v11);
  float* crow = cat + (long)pb * CH2;
  crow[c] = xv;
  crow[CH + c] = up;
}

// ---------------- LayerNorm(h2) * g + b, residual add into x ----------------
__global__ __launch_bounds__(256) void k_lnres(const float* __restrict__ h2,
                                               const float* __restrict__ g,
                                               const float* __restrict__ bt,
                                               float* __restrict__ xf) {
  int pb = blockIdx.x;
  int c = threadIdx.x;
  float v = h2[(long)pb * CH + c];
  __shared__ float red[256];
  float mu = blockSum(v, red) * (1.f / CH);
  float dv = v - mu;
  float var = blockSum(dv * dv, red) * (1.f / CH);
  float o = dv * rsqrtf(var + 1e-5f) * g[c] + bt[c];
  xf[(long)pb * CH + c] += o;
}

// ---------------- host-side orchestration ----------------
struct LayerP {
  const float *aggw, *qw, *kw, *vw, *mw, *w1, *w2, *g1, *b1, *g2, *b2;
};

static void enc_layer(float* x, float* src, const LayerP& p, bool rope,
                      float* qln, float* sln, float* qry, float* key, float* val,
                      float* msg, float* msg2, float* bufA, float* bufB,
                      const float* sinT, const float* cosT, hipStream_t stream) {
  // 1. aggregation + LN (conv for q from x, maxpool for s from src)
  k_agg<<<dim3(2 * BSZ * SL), 256, 0, stream>>>(x, src, p.aggw, p.g1, p.b1, qln, sln);
  // 2. Q/K/V projections (+RoPE for Q,K on self layers)
  dim3 gp(MATT / 64, CH / 64);
  if (rope) {
    k_gemm<2><<<gp, 256, 0, stream>>>(qln, p.qw, qry, MATT, CH, CH, sinT, cosT);
    k_gemm<2><<<gp, 256, 0, stream>>>(sln, p.kw, key, MATT, CH, CH, sinT, cosT);
  } else {
    k_gemm<0><<<gp, 256, 0, stream>>>(qln, p.qw, qry, MATT, CH, CH, nullptr, nullptr);
    k_gemm<0><<<gp, 256, 0, stream>>>(sln, p.kw, key, MATT, CH, CH, nullptr, nullptr);
  }
  k_gemm<0><<<gp, 256, 0, stream>>>(sln, p.vw, val, MATT, CH, CH, nullptr, nullptr);
  // 3-5. attention (scores in bufA, aliased with h1)
  k_scores<<<dim3(BSZ * NHD, SL / 64, SL / 64), 256, 0, stream>>>(qry, key, bufA);
  k_softmax<<<dim3(BSZ * NHD * SL), 256, 0, stream>>>(bufA);
  k_attnv<<<dim3(BSZ * NHD, SL / 64), 256, 0, stream>>>(bufA, val, msg);
  // 6. merge projection
  k_gemm<0><<<gp, 256, 0, stream>>>(msg, p.mw, msg2, MATT, CH, CH, nullptr, nullptr);
  // 7. upsample + concat (cat in bufB, aliased with h2)
  k_cat<<<dim3(BSZ * PIX), 256, 0, stream>>>(x, msg2, bufB);
  // 8. FFN1 + LeakyReLU (h1 in bufA)
  k_gemm<1><<<dim3(MFFN / 64, CH2 / 64), 256, 0, stream>>>(bufB, p.w1, bufA, MFFN, CH2, CH2, nullptr, nullptr);
  // 9. FFN2 (h2 in bufB; cat is dead by now)
  k_gemm<0><<<dim3(MFFN / 64, CH / 64), 256, 0, stream>>>(bufA, p.w2, bufB, MFFN, CH, CH2, nullptr, nullptr);
  // 10. LN + residual into x
  k_lnres<<<dim3(BSZ * PIX), 256, 0, stream>>>(bufB, p.g2, p.b2, x);
}

extern "C" void kernel_launch(void* const* d_in, const int* in_sizes, int n_in,
                              void* d_out, int out_size, void* d_ws, size_t ws_size,
                              hipStream_t stream) {
  const float* in_f0 = (const float*)d_in[0];
  const float* in_f1 = (const float*)d_in[1];
  const float* aggw  = (const float*)d_in[2];
  const float* qw    = (const float*)d_in[3];
  const float* kw    = (const float*)d_in[4];
  const float* vw    = (const float*)d_in[5];
  const float* mw    = (const float*)d_in[6];
  const float* w1    = (const float*)d_in[7];
  const float* w2    = (const float*)d_in[8];
  const float* g1    = (const float*)d_in[9];
  const float* b1    = (const float*)d_in[10];
  const float* g2    = (const float*)d_in[11];
  const float* b2    = (const float*)d_in[12];
  (void)in_sizes; (void)n_in; (void)out_size; (void)ws_size;

  // working feature maps (NHWC) live in d_out; final transpose stages via bufA
  float* f0 = (float*)d_out;
  float* f1 = f0 + FEATN;

  float* ws   = (float*)d_ws;
  float* qln  = ws;                   // 294912
  float* sln  = qln  + (long)MATT * CH;
  float* qry  = sln  + (long)MATT * CH;
  float* key  = qry  + (long)MATT * CH;
  float* val  = key  + (long)MATT * CH;
  float* msg  = val  + (long)MATT * CH;
  float* msg2 = msg  + (long)MATT * CH;
  float* sinT = msg2 + (long)MATT * CH;        // 147456
  float* cosT = sinT + (long)SL * CH;
  float* bufA = cosT + (long)SL * CH;          // 9,437,184 (scores | h1 | final NCHW staging)
  float* bufB = bufA + 2 * FEATN;              // 9,437,184 (cat | h2)

  // init: NCHW inputs -> NHWC working buffers, RoPE tables
  k_nchw2nhwc<<<dim3((unsigned)(FEATN / 256)), 256, 0, stream>>>(in_f0, f0);
  k_nchw2nhwc<<<dim3((unsigned)(FEATN / 256)), 256, 0, stream>>>(in_f1, f1);
  k_rope_tables<<<dim3(SL), 256, 0, stream>>>(sinT, cosT);

  for (int i = 0; i < 8; ++i) {
    LayerP p{aggw + (long)i * CH * 16,
             qw + (long)i * CH * CH, kw + (long)i * CH * CH,
             vw + (long)i * CH * CH, mw + (long)i * CH * CH,
             w1 + (long)i * CH2 * CH2, w2 + (long)i * CH2 * CH,
             g1 + i * CH, b1 + i * CH, g2 + i * CH, b2 + i * CH};
    if ((i & 1) == 0) {  // self
      enc_layer(f0, f0, p, true, qln, sln, qry, key, val, msg, msg2, bufA, bufB, sinT, cosT, stream);
      enc_layer(f1, f1, p, true, qln, sln, qry, key, val, msg, msg2, bufA, bufB, sinT, cosT, stream);
    } else {             // cross (second call uses updated f0 — matches reference)
      enc_layer(f0, f1, p, false, qln, sln, qry, key, val, msg, msg2, bufA, bufB, sinT, cosT, stream);
      enc_layer(f1, f0, p, false, qln, sln, qry, key, val, msg, msg2, bufA, bufB, sinT, cosT, stream);
    }
  }

  // final: NHWC -> NCHW into bufA staging, then copy into d_out
  k_nhwc2nchw<<<dim3((unsigned)(FEATN / 256)), 256, 0, stream>>>(f0, bufA);
  k_nhwc2nchw<<<dim3((unsigned)(FEATN / 256)), 256, 0, stream>>>(f1, bufA + FEATN);
  k_copy<<<dim3((unsigned)(2 * FEATN / 256)), 256, 0, stream>>>(bufA, (float*)d_out);
}

// Round 2
// 2903.692 us; speedup vs baseline: 2.1521x; 2.1521x over previous
//
#include <hip/hip_runtime.h>
#include <math.h>

// ---- problem constants ----
constexpr int BSZ = 2;            // batch
constexpr int CH  = 256;          // d_model
constexpr int IH  = 96, IW = 96;  // input H, W
constexpr int HSS = 24, WSS = 24; // aggregated H, W
constexpr int SL  = HSS * WSS;    // 576 tokens
constexpr int NHD = 8, DHD = 32;  // heads, head dim
constexpr int CH2 = 512;          // 2*d_model
constexpr int PIX = IH * IW;      // 9216
constexpr int MATT = BSZ * SL;    // 1152
constexpr int MFFN = BSZ * PIX;   // 18432
constexpr long FEATN = (long)BSZ * PIX * CH;  // 4,718,592 elements per feature

typedef __attribute__((ext_vector_type(8))) short bf16x8;
typedef __attribute__((ext_vector_type(4))) float f32x4;

__device__ inline unsigned short f2bf(float f) {
  unsigned u = __float_as_uint(f);
  u += 0x7FFFu + ((u >> 16) & 1u);   // RNE
  return (unsigned short)(u >> 16);
}

__device__ inline void gload16(const void* g, void* l) {
  __builtin_amdgcn_global_load_lds(
      (const __attribute__((address_space(1))) unsigned int*)g,
      (__attribute__((address_space(3))) unsigned int*)l, 16, 0, 0);
}

// ---------------- block reductions ----------------
__device__ inline float blockSum(float v, float* red) {
  int t = threadIdx.x;
  red[t] = v; __syncthreads();
  for (int s = 128; s > 0; s >>= 1) {
    if (t < s) red[t] += red[t + s];
    __syncthreads();
  }
  float r = red[0]; __syncthreads();
  return r;
}
__device__ inline float blockMax(float v, float* red) {
  int t = threadIdx.x;
  red[t] = v; __syncthreads();
  for (int s = 128; s > 0; s >>= 1) {
    if (t < s) red[t] = fmaxf(red[t], red[t + s]);
    __syncthreads();
  }
  float r = red[0]; __syncthreads();
  return r;
}

// ---------------- layout transforms ----------------
__global__ __launch_bounds__(256) void k_nchw2nhwc(const float* __restrict__ in,
                                                   float* __restrict__ out) {
  long idx = (long)blockIdx.x * 256 + threadIdx.x;  // over FEATN, c fastest
  int  c    = (int)(idx & (CH - 1));
  long rest = idx >> 8;            // b*PIX + p
  long p    = rest % PIX;
  long b    = rest / PIX;
  out[idx] = in[(b * CH + c) * PIX + p];
}

__global__ __launch_bounds__(256) void k_nhwc2nchw(const float* __restrict__ in,
                                                   float* __restrict__ out) {
  long idx = (long)blockIdx.x * 256 + threadIdx.x;  // over FEATN, p fastest
  long p    = idx % PIX;
  long rest = idx / PIX;
  int  c    = (int)(rest % CH);
  long b    = rest / CH;
  out[idx] = in[(b * PIX + p) * CH + c];
}

__global__ __launch_bounds__(256) void k_copy(const float* __restrict__ in,
                                              float* __restrict__ out) {
  long idx = (long)blockIdx.x * 256 + threadIdx.x;
  out[idx] = in[idx];
}

// ---------------- weight convert+transpose: W[K][N] f32 -> WT[N][K] bf16 ----------------
__global__ __launch_bounds__(256) void k_wt(const float* __restrict__ W,
                                            unsigned short* __restrict__ WT,
                                            int K, int N) {
  const long z = blockIdx.z;
  W  += z * (long)K * N;
  WT += z * (long)K * N;
  __shared__ float t[32][33];
  const int n0 = blockIdx.x * 32, k0 = blockIdx.y * 32;
  const int tx = threadIdx.x & 31, ty = threadIdx.x >> 5;  // ty 0..7
#pragma unroll
  for (int r = 0; r < 4; ++r)
    t[ty + r * 8][tx] = W[(long)(k0 + ty + r * 8) * N + n0 + tx];
  __syncthreads();
#pragma unroll
  for (int r = 0; r < 4; ++r)
    WT[(long)(n0 + ty + r * 8) * K + k0 + tx] = f2bf(t[tx][ty + r * 8]);
}

// ---------------- RoPE tables (same for all layers; 24x24 grid) ----------------
__global__ __launch_bounds__(256) void k_rope_tables(float* __restrict__ sinT,
                                                     float* __restrict__ cosT) {
  int l = blockIdx.x;      // 0..575
  int d = threadIdx.x;     // 0..255
  int ii = l / WSS + 1;
  int jj = l % WSS + 1;
  int kidx = d >> 2;                       // 0..63
  bool is_i = ((d >> 1) & 1) == 0;
  float div = expf((float)kidx * -0.14391156831212787f);  // -ln(10000)/64
  float pos = is_i ? (float)ii : (float)jj;
  float ang = pos * div;
  sinT[(long)l * CH + d] = sinf(ang);
  cosT[(long)l * CH + d] = cosf(ang);
}

// ---------------- aggregation: depthwise conv (q) / maxpool (s) + LayerNorm -> bf16 ----------------
__global__ __launch_bounds__(256) void k_agg(const float* __restrict__ x,
                                             const float* __restrict__ src,
                                             const float* __restrict__ aggw,
                                             const float* __restrict__ g,
                                             const float* __restrict__ bt,
                                             unsigned short* __restrict__ qln,
                                             unsigned short* __restrict__ sln) {
  int bi = blockIdx.x;
  int mode = 0;
  if (bi >= BSZ * SL) { mode = 1; bi -= BSZ * SL; }
  int b = bi / SL, l = bi % SL;
  int i = l / WSS, j = l % WSS;
  int c = threadIdx.x;
  const float* in = mode ? src : x;   // NHWC
  float v;
  if (mode == 0) {
    v = 0.f;
#pragma unroll
    for (int r = 0; r < 4; ++r)
#pragma unroll
      for (int s = 0; s < 4; ++s)
        v += in[(((long)b * IH + i * 4 + r) * IW + j * 4 + s) * CH + c] *
             aggw[c * 16 + r * 4 + s];
  } else {
    v = -INFINITY;
#pragma unroll
    for (int r = 0; r < 4; ++r)
#pragma unroll
      for (int s = 0; s < 4; ++s)
        v = fmaxf(v, in[(((long)b * IH + i * 4 + r) * IW + j * 4 + s) * CH + c]);
  }
  __shared__ float red[256];
  float mu = blockSum(v, red) * (1.f / CH);
  float dv = v - mu;
  float var = blockSum(dv * dv, red) * (1.f / CH);
  float o = dv * rsqrtf(var + 1e-5f) * g[c] + bt[c];
  (mode ? sln : qln)[(long)(b * SL + l) * CH + c] = f2bf(o);
}

// ---------------- bf16 MFMA GEMM: C[M,N] = A[M,K] @ Bt[N,K]^T ----------------
// A bf16 row-major [M][K]; Bt bf16 row-major [N][K] (pre-transposed weights).
// EPI: 0 none, 1 LeakyReLU, 2 RoPE. OBF: 1 -> bf16 output, 0 -> f32.
template <int BM, int BN, int EPI, int OBF>
__global__ __launch_bounds__(256) void k_mm(const unsigned short* __restrict__ A,
                                            const unsigned short* __restrict__ Bt,
                                            void* __restrict__ Cout,
                                            int M, int N, int K,
                                            const float* __restrict__ sinT,
                                            const float* __restrict__ cosT) {
  constexpr int BK = 64;
  constexpr int WM = BM / 2, WN = BN / 2;      // 2x2 waves
  constexpr int FM = WM / 16, FN = WN / 16;
  __shared__ unsigned short As[BM * BK];
  __shared__ unsigned short Bs[BN * BK];
  const int tid = threadIdx.x;
  const int lane = tid & 63, w = tid >> 6;
  const int wr = w >> 1, wc = w & 1;
  const int lrow = lane & 15, kgrp = lane >> 4;
  const int bm = blockIdx.x * BM, bn = blockIdx.y * BN;

  f32x4 acc[FM][FN] = {};
  for (int k0 = 0; k0 < K; k0 += BK) {
    constexpr int RA = BM * BK / (256 * 8);
#pragma unroll
    for (int i = 0; i < RA; ++i) {
      int e = (i * 256 + tid) * 8;
      gload16(A + (size_t)(bm + (e >> 6)) * K + k0 + (e & 63), &As[e]);
    }
    constexpr int RB = BN * BK / (256 * 8);
#pragma unroll
    for (int i = 0; i < RB; ++i) {
      int e = (i * 256 + tid) * 8;
      gload16(Bt + (size_t)(bn + (e >> 6)) * K + k0 + (e & 63), &Bs[e]);
    }
    asm volatile("s_waitcnt vmcnt(0)" ::: "memory");
    __syncthreads();
#pragma unroll
    for (int ks = 0; ks < 2; ++ks) {
      bf16x8 a[FM], b[FN];
#pragma unroll
      for (int m = 0; m < FM; ++m)
        a[m] = *(const bf16x8*)&As[(wr * WM + m * 16 + lrow) * BK + ks * 32 + kgrp * 8];
#pragma unroll
      for (int n = 0; n < FN; ++n)
        b[n] = *(const bf16x8*)&Bs[(wc * WN + n * 16 + lrow) * BK + ks * 32 + kgrp * 8];
#pragma unroll
      for (int m = 0; m < FM; ++m)
#pragma unroll
        for (int n = 0; n < FN; ++n)
          acc[m][n] = __builtin_amdgcn_mfma_f32_16x16x32_bf16(a[m], b[n], acc[m][n], 0, 0, 0);
    }
    __syncthreads();
  }
  // epilogue: C/D layout col = lane&15, row = (lane>>4)*4 + reg
#pragma unroll
  for (int m = 0; m < FM; ++m) {
    const int rowb = bm + wr * WM + m * 16 + kgrp * 4;
#pragma unroll
    for (int n = 0; n < FN; ++n) {
      const int col = bn + wc * WN + n * 16 + lrow;
#pragma unroll
      for (int r = 0; r < 4; ++r) {
        const int row = rowb + r;
        float v = acc[m][n][r];
        if (EPI == 1) v = v >= 0.f ? v : 0.01f * v;
        if (EPI == 2) {
          float vp = __shfl_xor(v, 1);  // partner column (col^1, same row)
          int l = row % SL;
          float s = sinT[(long)l * CH + col];
          float c = cosT[(long)l * CH + col];
          v = ((lane & 1) == 0) ? v * c - vp * s : v * c + vp * s;
        }
        if (OBF)
          ((unsigned short*)Cout)[(size_t)row * N + col] = f2bf(v);
        else
          ((float*)Cout)[(size_t)row * N + col] = v;
      }
    }
  }
}

// ---------------- attention scores: sc[bh, l, s] = q·k / sqrt(dh) ----------------
__global__ __launch_bounds__(256) void k_scores(const float* __restrict__ q,
                                                const float* __restrict__ k,
                                                float* __restrict__ sc) {
  const int bh = blockIdx.x;
  const int b = bh >> 3, h = bh & 7;
  const int mB = blockIdx.y * 64, nB = blockIdx.z * 64;
  __shared__ float Qs[64][33];
  __shared__ float Ks[64][33];
  const int tid = threadIdx.x;
#pragma unroll
  for (int i = 0; i < 8; ++i) {
    int idx = tid + i * 256;
    int d = idx & 31, r = idx >> 5;
    Qs[r][d] = q[(long)(b * SL + mB + r) * CH + h * DHD + d];
    Ks[r][d] = k[(long)(b * SL + nB + r) * CH + h * DHD + d];
  }
  __syncthreads();
  const int tx = tid & 15, ty = tid >> 4;
  float acc[4][4] = {};
#pragma unroll
  for (int kk = 0; kk < 32; ++kk) {
    float a[4], bb[4];
#pragma unroll
    for (int i = 0; i < 4; ++i) a[i] = Qs[ty * 4 + i][kk];
#pragma unroll
    for (int j = 0; j < 4; ++j) bb[j] = Ks[tx * 4 + j][kk];
#pragma unroll
    for (int i = 0; i < 4; ++i)
#pragma unroll
      for (int j = 0; j < 4; ++j) acc[i][j] += a[i] * bb[j];
  }
  const float scale = 0.17677669529663687f;  // 1/sqrt(32)
#pragma unroll
  for (int i = 0; i < 4; ++i) {
    long row = (long)bh * SL + mB + ty * 4 + i;
    float4 ov = make_float4(acc[i][0] * scale, acc[i][1] * scale,
                            acc[i][2] * scale, acc[i][3] * scale);
    *reinterpret_cast<float4*>(&sc[row * SL + nB + tx * 4]) = ov;
  }
}

// ---------------- row softmax over S=576 ----------------
__global__ __launch_bounds__(256) void k_softmax(float* __restrict__ sc) {
  __shared__ float red[256];
  long row = blockIdx.x;
  float* p = sc + row * SL;
  int t = threadIdx.x;
  float mx = -1e30f;
  for (int i = t; i < SL; i += 256) mx = fmaxf(mx, p[i]);
  float m = blockMax(mx, red);
  float s = 0.f;
  for (int i = t; i < SL; i += 256) {
    float e = expf(p[i] - m);
    p[i] = e;
    s += e;
  }
  float tot = blockSum(s, red);
  float inv = 1.f / tot;
  for (int i = t; i < SL; i += 256) p[i] *= inv;
}

// ---------------- attn @ V -> msg[b, l, h*32+d] (bf16 out) ----------------
__global__ __launch_bounds__(256) void k_attnv(const float* __restrict__ att,
                                               const float* __restrict__ v,
                                               unsigned short* __restrict__ out) {
  const int bh = blockIdx.x;
  const int b = bh >> 3, h = bh & 7;
  const int mB = blockIdx.y * 64;
  const int tid = threadIdx.x;
  const int d = tid & 31, q8 = tid >> 5;
  __shared__ float As[64][65];
  __shared__ float Vs[64][33];
  float acc[8] = {};
  for (int s0 = 0; s0 < SL; s0 += 64) {
#pragma unroll
    for (int i = 0; i < 16; ++i) {
      int idx = tid + i * 256;
      int cc = idx & 63, r = idx >> 6;
      As[r][cc] = att[((long)bh * SL + mB + r) * SL + s0 + cc];
    }
#pragma unroll
    for (int i = 0; i < 8; ++i) {
      int idx = tid + i * 256;
      int dd = idx & 31, r = idx >> 5;
      Vs[r][dd] = v[(long)(b * SL + s0 + r) * CH + h * DHD + dd];
    }
    __syncthreads();
#pragma unroll
    for (int r = 0; r < 8; ++r) {
      int lr = q8 * 8 + r;
      float a = 0.f;
#pragma unroll
      for (int ss = 0; ss < 64; ++ss) a += As[lr][ss] * Vs[ss][d];
      acc[r] += a;
    }
    __syncthreads();
  }
#pragma unroll
  for (int r = 0; r < 8; ++r)
    out[(long)(b * SL + mB + q8 * 8 + r) * CH + h * DHD + d] = f2bf(acc[r]);
}

// ---------------- bilinear upsample x4 + concat [x, up] -> cat[pix, 512] bf16 ----------------
__global__ __launch_bounds__(256) void k_cat(const float* __restrict__ xf,
                                             const float* __restrict__ m2,
                                             unsigned short* __restrict__ cat) {
  int pb = blockIdx.x;                 // b*PIX + p
  int b = pb / PIX, p = pb % PIX;
  int y = p / IW, xx = p % IW;
  int c = threadIdx.x;
  float xv = xf[(long)pb * CH + c];
  float sy = (y + 0.5f) * 0.25f - 0.5f;
  float sx = (xx + 0.5f) * 0.25f - 0.5f;
  int y0 = (int)floorf(sy); float wy = sy - y0;
  int x0 = (int)floorf(sx); float wx = sx - x0;
  int y1 = min(y0 + 1, HSS - 1); y0 = max(y0, 0);
  int x1 = min(x0 + 1, WSS - 1); x0 = max(x0, 0);
  const float* mb = m2 + (long)b * SL * CH;
  float v00 = mb[(y0 * WSS + x0) * CH + c];
  float v01 = mb[(y0 * WSS + x1) * CH + c];
  float v10 = mb[(y1 * WSS + x0) * CH + c];
  float v11 = mb[(y1 * WSS + x1) * CH + c];
  float up = (1.f - wy) * ((1.f - wx) * v00 + wx * v01) +
             wy * ((1.f - wx) * v10 + wx * v11);
  unsigned short* crow = cat + (long)pb * CH2;
  crow[c] = f2bf(xv);
  crow[CH + c] = f2bf(up);
}

// ---------------- LayerNorm(h2) * g + b, residual add into x ----------------
__global__ __launch_bounds__(256) void k_lnres(const float* __restrict__ h2,
                                               const float* __restrict__ g,
                                               const float* __restrict__ bt,
                                               float* __restrict__ xf) {
  int pb = blockIdx.x;
  int c = threadIdx.x;
  float v = h2[(long)pb * CH + c];
  __shared__ float red[256];
  float mu = blockSum(v, red) * (1.f / CH);
  float dv = v - mu;
  float var = blockSum(dv * dv, red) * (1.f / CH);
  float o = dv * rsqrtf(var + 1e-5f) * g[c] + bt[c];
  xf[(long)pb * CH + c] += o;
}

// ---------------- host-side orchestration ----------------
struct LayerP {
  const float *aggw, *g1, *b1, *g2, *b2;
  const unsigned short *qwT, *kwT, *vwT, *mwT, *w1T, *w2T;
};

struct Bufs {
  unsigned short *qln, *sln, *msg, *cat, *h1;
  float *qry, *key, *val, *msg2, *scores, *h2;
  const float *sinT, *cosT;
};

static void enc_layer(float* x, float* src, const LayerP& p, bool rope,
                      const Bufs& B, hipStream_t stream) {
  // 1. aggregation + LN (conv for q from x, maxpool for s from src) -> bf16
  k_agg<<<dim3(2 * BSZ * SL), 256, 0, stream>>>(x, src, p.aggw, p.g1, p.b1, B.qln, B.sln);
  // 2. Q/K/V projections (+RoPE for Q,K on self layers) — bf16 MFMA
  dim3 gp(MATT / 64, CH / 64);
  if (rope) {
    k_mm<64, 64, 2, 0><<<gp, 256, 0, stream>>>(B.qln, p.qwT, B.qry, MATT, CH, CH, B.sinT, B.cosT);
    k_mm<64, 64, 2, 0><<<gp, 256, 0, stream>>>(B.sln, p.kwT, B.key, MATT, CH, CH, B.sinT, B.cosT);
  } else {
    k_mm<64, 64, 0, 0><<<gp, 256, 0, stream>>>(B.qln, p.qwT, B.qry, MATT, CH, CH, nullptr, nullptr);
    k_mm<64, 64, 0, 0><<<gp, 256, 0, stream>>>(B.sln, p.kwT, B.key, MATT, CH, CH, nullptr, nullptr);
  }
  k_mm<64, 64, 0, 0><<<gp, 256, 0, stream>>>(B.sln, p.vwT, B.val, MATT, CH, CH, nullptr, nullptr);
  // 3-5. attention (f32 vector path; scores aliases h2/h1 region)
  k_scores<<<dim3(BSZ * NHD, SL / 64, SL / 64), 256, 0, stream>>>(B.qry, B.key, B.scores);
  k_softmax<<<dim3(BSZ * NHD * SL), 256, 0, stream>>>(B.scores);
  k_attnv<<<dim3(BSZ * NHD, SL / 64), 256, 0, stream>>>(B.scores, B.val, B.msg);
  // 6. merge projection
  k_mm<64, 64, 0, 0><<<gp, 256, 0, stream>>>(B.msg, p.mwT, B.msg2, MATT, CH, CH, nullptr, nullptr);
  // 7. upsample + concat -> bf16 cat
  k_cat<<<dim3(BSZ * PIX), 256, 0, stream>>>(x, B.msg2, B.cat);
  // 8. FFN1 + LeakyReLU -> bf16 h1
  k_mm<128, 128, 1, 1><<<dim3(MFFN / 128, CH2 / 128), 256, 0, stream>>>(
      B.cat, p.w1T, B.h1, MFFN, CH2, CH2, nullptr, nullptr);
  // 9. FFN2 -> f32 h2
  k_mm<128, 128, 0, 0><<<dim3(MFFN / 128, CH / 128), 256, 0, stream>>>(
      B.h1, p.w2T, B.h2, MFFN, CH, CH2, nullptr, nullptr);
  // 10. LN + residual into x
  k_lnres<<<dim3(BSZ * PIX), 256, 0, stream>>>(B.h2, p.g2, p.b2, x);
}

extern "C" void kernel_launch(void* const* d_in, const int* in_sizes, int n_in,
                              void* d_out, int out_size, void* d_ws, size_t ws_size,
                              hipStream_t stream) {
  const float* in_f0 = (const float*)d_in[0];
  const float* in_f1 = (const float*)d_in[1];
  const float* aggw  = (const float*)d_in[2];
  const float* qw    = (const float*)d_in[3];
  const float* kw    = (const float*)d_in[4];
  const float* vw    = (const float*)d_in[5];
  const float* mw    = (const float*)d_in[6];
  const float* w1    = (const float*)d_in[7];
  const float* w2    = (const float*)d_in[8];
  const float* g1    = (const float*)d_in[9];
  const float* b1    = (const float*)d_in[10];
  const float* g2    = (const float*)d_in[11];
  const float* b2    = (const float*)d_in[12];
  (void)in_sizes; (void)n_in; (void)out_size; (void)ws_size;

  // working feature maps (NHWC) live in d_out
  float* f0 = (float*)d_out;
  float* f1 = f0 + FEATN;

  // ---- ws layout (≈74.8 MB total; round-1 proved ≥85 MB usable) ----
  char* cur = (char*)d_ws;
  auto alloc = [&](size_t bytes) { void* p = cur; cur += bytes; return p; };
  float* X = (float*)alloc((size_t)2 * FEATN * 4);  // scores | h2 | h1(top half) | final staging
  float*          scores = X;                        // 21.2 MB, live steps 3-5
  float*          h2     = X;                        // 18.9 MB, live steps 9-10
  unsigned short* h1     = (unsigned short*)(X + FEATN);  // 18.9 MB, live steps 8-9
  float*          stage  = X;                        // final transpose staging (37.7 MB)
  unsigned short* cat  = (unsigned short*)alloc((size_t)MFFN * CH2 * 2);
  unsigned short* qln  = (unsigned short*)alloc((size_t)MATT * CH * 2);
  unsigned short* sln  = (unsigned short*)alloc((size_t)MATT * CH * 2);
  unsigned short* msg  = (unsigned short*)alloc((size_t)MATT * CH * 2);
  float* qry  = (float*)alloc((size_t)MATT * CH * 4);
  float* key  = (float*)alloc((size_t)MATT * CH * 4);
  float* val  = (float*)alloc((size_t)MATT * CH * 4);
  float* msg2 = (float*)alloc((size_t)MATT * CH * 4);
  float* sinT = (float*)alloc((size_t)SL * CH * 4);
  float* cosT = (float*)alloc((size_t)SL * CH * 4);
  unsigned short* qwT = (unsigned short*)alloc((size_t)8 * CH * CH * 2);
  unsigned short* kwT = (unsigned short*)alloc((size_t)8 * CH * CH * 2);
  unsigned short* vwT = (unsigned short*)alloc((size_t)8 * CH * CH * 2);
  unsigned short* mwT = (unsigned short*)alloc((size_t)8 * CH * CH * 2);
  unsigned short* w1T = (unsigned short*)alloc((size_t)8 * CH2 * CH2 * 2);
  unsigned short* w2T = (unsigned short*)alloc((size_t)8 * CH * CH2 * 2);

  // init: NCHW -> NHWC, RoPE tables, weight convert+transpose
  k_nchw2nhwc<<<dim3((unsigned)(FEATN / 256)), 256, 0, stream>>>(in_f0, f0);
  k_nchw2nhwc<<<dim3((unsigned)(FEATN / 256)), 256, 0, stream>>>(in_f1, f1);
  k_rope_tables<<<dim3(SL), 256, 0, stream>>>(sinT, cosT);
  k_wt<<<dim3(CH / 32, CH / 32, 8), 256, 0, stream>>>(qw, qwT, CH, CH);
  k_wt<<<dim3(CH / 32, CH / 32, 8), 256, 0, stream>>>(kw, kwT, CH, CH);
  k_wt<<<dim3(CH / 32, CH / 32, 8), 256, 0, stream>>>(vw, vwT, CH, CH);
  k_wt<<<dim3(CH / 32, CH / 32, 8), 256, 0, stream>>>(mw, mwT, CH, CH);
  k_wt<<<dim3(CH2 / 32, CH2 / 32, 8), 256, 0, stream>>>(w1, w1T, CH2, CH2);
  k_wt<<<dim3(CH / 32, CH2 / 32, 8), 256, 0, stream>>>(w2, w2T, CH2, CH);

  Bufs B{qln, sln, msg, cat, h1, qry, key, val, msg2, scores, h2, sinT, cosT};

  for (int i = 0; i < 8; ++i) {
    LayerP p{aggw + (long)i * CH * 16,
             g1 + i * CH, b1 + i * CH, g2 + i * CH, b2 + i * CH,
             qwT + (long)i * CH * CH, kwT + (long)i * CH * CH,
             vwT + (long)i * CH * CH, mwT + (long)i * CH * CH,
             w1T + (long)i * CH2 * CH2, w2T + (long)i * CH * CH2};
    if ((i & 1) == 0) {  // self
      enc_layer(f0, f0, p, true, B, stream);
      enc_layer(f1, f1, p, true, B, stream);
    } else {             // cross (second call uses updated f0 — matches reference)
      enc_layer(f0, f1, p, false, B, stream);
      enc_layer(f1, f0, p, false, B, stream);
    }
  }

  // final: NHWC -> NCHW into staging, then copy into d_out
  k_nhwc2nchw<<<dim3((unsigned)(FEATN / 256)), 256, 0, stream>>>(f0, stage);
  k_nhwc2nchw<<<dim3((unsigned)(FEATN / 256)), 256, 0, stream>>>(f1, stage + FEATN);
  k_copy<<<dim3((unsigned)(2 * FEATN / 256)), 256, 0, stream>>>(stage, (float*)d_out);
}

// Round 3
// 1681.786 us; speedup vs baseline: 3.7157x; 1.7266x over previous
//
#include <hip/hip_runtime.h>
#include <math.h>

// ---- problem constants ----
constexpr int BSZ = 2;            // batch
constexpr int CH  = 256;          // d_model
constexpr int IH  = 96, IW = 96;  // input H, W
constexpr int HSS = 24, WSS = 24; // aggregated H, W
constexpr int SL  = HSS * WSS;    // 576 tokens
constexpr int NHD = 8, DHD = 32;  // heads, head dim
constexpr int CH2 = 512;          // 2*d_model
constexpr int PIX = IH * IW;      // 9216
constexpr int MFFN = BSZ * PIX;   // 18432
constexpr long FEATN = (long)BSZ * PIX * CH;  // 4,718,592 per feature

typedef __attribute__((ext_vector_type(8))) short bf16x8;
typedef __attribute__((ext_vector_type(4))) float f32x4;
typedef _Float16 f16;
typedef __attribute__((ext_vector_type(8))) _Float16 f16x8;
typedef __attribute__((ext_vector_type(4))) _Float16 f16x4;

__device__ inline unsigned short f2bf(float f) {
  unsigned u = __float_as_uint(f);
  u += 0x7FFFu + ((u >> 16) & 1u);   // RNE
  return (unsigned short)(u >> 16);
}

__device__ inline void gload16(const void* g, void* l) {
  __builtin_amdgcn_global_load_lds(
      (const __attribute__((address_space(1))) unsigned int*)g,
      (__attribute__((address_space(3))) unsigned int*)l, 16, 0, 0);
}

// ---------------- block reductions ----------------
__device__ inline float blockSum(float v, float* red) {
  int t = threadIdx.x;
  red[t] = v; __syncthreads();
  for (int s = 128; s > 0; s >>= 1) {
    if (t < s) red[t] += red[t + s];
    __syncthreads();
  }
  float r = red[0]; __syncthreads();
  return r;
}

// ---------------- layout transforms ----------------
__global__ __launch_bounds__(256) void k_nchw2nhwc(const float* __restrict__ in,
                                                   float* __restrict__ out) {
  long idx = (long)blockIdx.x * 256 + threadIdx.x;
  int  c    = (int)(idx & (CH - 1));
  long rest = idx >> 8;
  long p    = rest % PIX;
  long b    = rest / PIX;
  out[idx] = in[(b * CH + c) * PIX + p];
}

__global__ __launch_bounds__(256) void k_nhwc2nchw(const float* __restrict__ in,
                                                   float* __restrict__ out) {
  long idx = (long)blockIdx.x * 256 + threadIdx.x;
  long p    = idx % PIX;
  long rest = idx / PIX;
  int  c    = (int)(rest % CH);
  long b    = rest / CH;
  out[idx] = in[(b * PIX + p) * CH + c];
}

__global__ __launch_bounds__(256) void k_copy(const float* __restrict__ in,
                                              float* __restrict__ out) {
  long idx = (long)blockIdx.x * 256 + threadIdx.x;
  out[idx] = in[idx];
}

// ---------------- weight convert+transpose: W[K][N] f32 -> WT[N][K] bf16 ----------------
__global__ __launch_bounds__(256) void k_wt(const float* __restrict__ W,
                                            unsigned short* __restrict__ WT,
                                            int K, int N, long strideW, long strideT) {
  const long z = blockIdx.z;
  W  += z * strideW;
  WT += z * strideT;
  __shared__ float t[32][33];
  const int n0 = blockIdx.x * 32, k0 = blockIdx.y * 32;
  const int tx = threadIdx.x & 31, ty = threadIdx.x >> 5;  // ty 0..7
#pragma unroll
  for (int r = 0; r < 4; ++r)
    t[ty + r * 8][tx] = W[(long)(k0 + ty + r * 8) * N + n0 + tx];
  __syncthreads();
#pragma unroll
  for (int r = 0; r < 4; ++r)
    WT[(long)(n0 + ty + r * 8) * K + k0 + tx] = f2bf(t[tx][ty + r * 8]);
}

// ---------------- RoPE tables (24x24 grid) ----------------
__global__ __launch_bounds__(256) void k_rope_tables(float* __restrict__ sinT,
                                                     float* __restrict__ cosT) {
  int l = blockIdx.x;      // 0..575
  int d = threadIdx.x;     // 0..255
  int ii = l / WSS + 1;
  int jj = l % WSS + 1;
  int kidx = d >> 2;
  bool is_i = ((d >> 1) & 1) == 0;
  float div = expf((float)kidx * -0.14391156831212787f);  // -ln(10000)/64
  float pos = is_i ? (float)ii : (float)jj;
  float ang = pos * div;
  sinT[(long)l * CH + d] = sinf(ang);
  cosT[(long)l * CH + d] = cosf(ang);
}

// ---------------- aggregation: depthwise conv / maxpool + LayerNorm -> bf16 ----------------
__global__ __launch_bounds__(256) void k_agg(const float* __restrict__ x,
                                             const float* __restrict__ src,
                                             const float* __restrict__ aggw,
                                             const float* __restrict__ g,
                                             const float* __restrict__ bt,
                                             unsigned short* __restrict__ qln,
                                             unsigned short* __restrict__ sln,
                                             int nb) {
  int bi = blockIdx.x;
  int mode = 0;
  if (bi >= nb * SL) { mode = 1; bi -= nb * SL; }
  int b = bi / SL, l = bi % SL;
  int i = l / WSS, j = l % WSS;
  int c = threadIdx.x;
  const float* in = mode ? src : x;   // NHWC
  float v;
  if (mode == 0) {
    v = 0.f;
#pragma unroll
    for (int r = 0; r < 4; ++r)
#pragma unroll
      for (int s = 0; s < 4; ++s)
        v += in[(((long)b * IH + i * 4 + r) * IW + j * 4 + s) * CH + c] *
             aggw[c * 16 + r * 4 + s];
  } else {
    v = -INFINITY;
#pragma unroll
    for (int r = 0; r < 4; ++r)
#pragma unroll
      for (int s = 0; s < 4; ++s)
        v = fmaxf(v, in[(((long)b * IH + i * 4 + r) * IW + j * 4 + s) * CH + c]);
  }
  __shared__ float red[256];
  float mu = blockSum(v, red) * (1.f / CH);
  float dv = v - mu;
  float var = blockSum(dv * dv, red) * (1.f / CH);
  float o = dv * rsqrtf(var + 1e-5f) * g[c] + bt[c];
  (mode ? sln : qln)[(long)(b * SL + l) * CH + c] = f2bf(o);
}

// ---------------- bf16 MFMA GEMM: C[M,N] = A[M,K] @ Bt[N,K]^T ----------------
// EPI: 0 none, 1 LeakyReLU.
// OUT: 0 f32 [row][N]; 1 bf16 [row][N];
//      2 Q-mode: f16 per-head qh[b][h][s][32], optional RoPE, * 1/sqrt(32)
//      3 KV-mode: col<256 -> K (opt RoPE) f16 kh[b][h][s][32]; col>=256 -> V f16 vt[b][h][32][576]
template <int BM, int BN, int EPI, int OUT>
__global__ __launch_bounds__(256) void k_mm(const unsigned short* __restrict__ A,
                                            const unsigned short* __restrict__ Bt,
                                            void* __restrict__ Cout,
                                            void* __restrict__ Cout2,
                                            int M, int N, int K,
                                            const float* __restrict__ sinT,
                                            const float* __restrict__ cosT) {
  constexpr int BK = 64;
  constexpr int WM = BM / 2, WN = BN / 2;      // 2x2 waves
  constexpr int FM = WM / 16, FN = WN / 16;
  __shared__ unsigned short As[BM * BK];
  __shared__ unsigned short Bs[BN * BK];
  const int tid = threadIdx.x;
  const int lane = tid & 63, w = tid >> 6;
  const int wr = w >> 1, wc = w & 1;
  const int lq = lane & 15, g = lane >> 4;
  const int bm = blockIdx.x * BM, bn = blockIdx.y * BN;

  f32x4 acc[FM][FN] = {};
  for (int k0 = 0; k0 < K; k0 += BK) {
    constexpr int RA = BM * BK / (256 * 8);
#pragma unroll
    for (int i = 0; i < RA; ++i) {
      int e = (i * 256 + tid) * 8;
      gload16(A + (size_t)(bm + (e >> 6)) * K + k0 + (e & 63), &As[e]);
    }
    constexpr int RB = BN * BK / (256 * 8);
#pragma unroll
    for (int i = 0; i < RB; ++i) {
      int e = (i * 256 + tid) * 8;
      gload16(Bt + (size_t)(bn + (e >> 6)) * K + k0 + (e & 63), &Bs[e]);
    }
    asm volatile("s_waitcnt vmcnt(0)" ::: "memory");
    __syncthreads();
#pragma unroll
    for (int ks = 0; ks < 2; ++ks) {
      bf16x8 a[FM], b[FN];
#pragma unroll
      for (int m = 0; m < FM; ++m)
        a[m] = *(const bf16x8*)&As[(wr * WM + m * 16 + lq) * BK + ks * 32 + g * 8];
#pragma unroll
      for (int n = 0; n < FN; ++n)
        b[n] = *(const bf16x8*)&Bs[(wc * WN + n * 16 + lq) * BK + ks * 32 + g * 8];
#pragma unroll
      for (int m = 0; m < FM; ++m)
#pragma unroll
        for (int n = 0; n < FN; ++n)
          acc[m][n] = __builtin_amdgcn_mfma_f32_16x16x32_bf16(a[m], b[n], acc[m][n], 0, 0, 0);
    }
    __syncthreads();
  }
  // epilogue: D layout col = lane&15 (B/n index), row = (lane>>4)*4 + r (A/m index)
#pragma unroll
  for (int m = 0; m < FM; ++m) {
    const int rowb = bm + wr * WM + m * 16 + g * 4;
#pragma unroll
    for (int n = 0; n < FN; ++n) {
      const int col = bn + wc * WN + n * 16 + lq;
#pragma unroll
      for (int r = 0; r < 4; ++r) {
        const int row = rowb + r;
        float v = acc[m][n][r];
        if (EPI == 1) v = v >= 0.f ? v : 0.01f * v;
        if (OUT == 0) {
          ((float*)Cout)[(size_t)row * N + col] = v;
        } else if (OUT == 1) {
          ((unsigned short*)Cout)[(size_t)row * N + col] = f2bf(v);
        } else {
          const int b = row / SL, s = row - b * SL;
          const bool isK = (OUT == 2) || (col < CH);
          const int ch = isK ? col : col - CH;
          float vp = __shfl_xor(v, 1);  // partner channel (ch^1)
          if (isK && sinT) {
            float sn = sinT[(size_t)s * CH + ch];
            float cs = cosT[(size_t)s * CH + ch];
            v = ((lane & 1) == 0) ? v * cs - vp * sn : v * cs + vp * sn;
          }
          if (OUT == 2) v *= 0.17677669529663687f;  // 1/sqrt(32) folded into Q
          const int h = ch >> 5, d = ch & 31;
          if (isK)
            ((f16*)Cout)[(((size_t)b * NHD + h) * SL + s) * DHD + d] = (f16)v;
          else
            ((f16*)Cout2)[(((size_t)b * NHD + h) * DHD + d) * SL + s] = (f16)v;
        }
      }
    }
  }
}

// ---------------- fused flash attention ----------------
// qh,kh: f16 [bh][576][32]; vt: f16 [bh][32][576]; msg: bf16 [token][256]
// grid (nb*8, 9), block 256 = 4 independent waves; wave = 16 q-rows.
__global__ __launch_bounds__(256) void k_attn(const f16* __restrict__ qh,
                                              const f16* __restrict__ kh,
                                              const f16* __restrict__ vt,
                                              unsigned short* __restrict__ msg) {
  const int bh = blockIdx.x;
  const int b = bh >> 3, h = bh & 7;
  const int wid = threadIdx.x >> 6, lane = threadIdx.x & 63;
  const int lq = lane & 15, g = lane >> 4;
  const int q0 = (blockIdx.y * 4 + wid) * 16;

  const f16x8 qf = *(const f16x8*)&qh[((size_t)bh * SL + q0 + lq) * DHD + g * 8];
  const f16* kbase = kh + (size_t)bh * SL * DHD;
  const f16* vbase = vt + (size_t)bh * DHD * SL;

  f32x4 o0 = {}, o1 = {};          // O^T[d][q]: d-tiles 0-15, 16-31; col q = lq
  float m = -1e30f, l = 0.f;
  for (int t = 0; t < 36; ++t) {
    // S^T tile: mfma(A=K rows, B=Q rows) -> col=q=lq, row = s = t*16 + g*4 + r
    f16x8 kf = *(const f16x8*)&kbase[((size_t)(t * 16 + lq)) * DHD + g * 8];
    f32x4 s = __builtin_amdgcn_mfma_f32_16x16x32_f16(kf, qf, (f32x4){0.f, 0.f, 0.f, 0.f}, 0, 0, 0);
    float tm = fmaxf(fmaxf(s[0], s[1]), fmaxf(s[2], s[3]));
    tm = fmaxf(tm, __shfl_xor(tm, 16));
    tm = fmaxf(tm, __shfl_xor(tm, 32));   // all 4 groups now share per-q tile max
    if (__any(tm > m + 5.f)) {            // deferred-max rescale (THR=5)
      float mn = fmaxf(m, tm);
      float f = __expf(m - mn);
      o0 *= f; o1 *= f; l *= f; m = mn;
    }
    float e0 = __expf(s[0] - m), e1 = __expf(s[1] - m);
    float e2 = __expf(s[2] - m), e3 = __expf(s[3] - m);
    l += (e0 + e1) + (e2 + e3);
    f16x4 ef = {(f16)e0, (f16)e1, (f16)e2, (f16)e3};  // B-frag: n=q=lq, k = g*4+r  (exact match)
    f16x4 va = *(const f16x4*)&vbase[(size_t)lq * SL + t * 16 + g * 4];
    f16x4 vb = *(const f16x4*)&vbase[(size_t)(16 + lq) * SL + t * 16 + g * 4];
    o0 = __builtin_amdgcn_mfma_f32_16x16x16f16(va, ef, o0, 0, 0, 0);
    o1 = __builtin_amdgcn_mfma_f32_16x16x16f16(vb, ef, o1, 0, 0, 0);
  }
  l += __shfl_xor(l, 16);
  l += __shfl_xor(l, 32);
  float inv = 1.f / l;
  // O^T rows: d = mt*16 + g*4 + r, col q = lq -> msg[b*576+q0+lq][h*32+d]
  unsigned short* mrow = msg + ((size_t)(b * SL + q0 + lq)) * CH + h * DHD;
#pragma unroll
  for (int mt = 0; mt < 2; ++mt) {
    f32x4 o = mt ? o1 : o0;
    unsigned a0 = f2bf(o[0] * inv) | ((unsigned)f2bf(o[1] * inv) << 16);
    unsigned a1 = f2bf(o[2] * inv) | ((unsigned)f2bf(o[3] * inv) << 16);
    uint2 u; u.x = a0; u.y = a1;
    *(uint2*)&mrow[mt * 16 + g * 4] = u;
  }
}

// ---------------- bilinear upsample x4 + concat [x, up] -> cat[pix, 512] bf16 ----------------
__global__ __launch_bounds__(256) void k_cat(const float* __restrict__ xf,
                                             const float* __restrict__ m2,
                                             unsigned short* __restrict__ cat) {
  int pb = blockIdx.x;                 // b*PIX + p
  int b = pb / PIX, p = pb % PIX;
  int y = p / IW, xx = p % IW;
  int c = threadIdx.x;
  float xv = xf[(long)pb * CH + c];
  float sy = (y + 0.5f) * 0.25f - 0.5f;
  float sx = (xx + 0.5f) * 0.25f - 0.5f;
  int y0 = (int)floorf(sy); float wy = sy - y0;
  int x0 = (int)floorf(sx); float wx = sx - x0;
  int y1 = min(y0 + 1, HSS - 1); y0 = max(y0, 0);
  int x1 = min(x0 + 1, WSS - 1); x0 = max(x0, 0);
  const float* mb = m2 + (long)b * SL * CH;
  float v00 = mb[(y0 * WSS + x0) * CH + c];
  float v01 = mb[(y0 * WSS + x1) * CH + c];
  float v10 = mb[(y1 * WSS + x0) * CH + c];
  float v11 = mb[(y1 * WSS + x1) * CH + c];
  float up = (1.f - wy) * ((1.f - wx) * v00 + wx * v01) +
             wy * ((1.f - wx) * v10 + wx * v11);
  unsigned short* crow = cat + (long)pb * CH2;
  crow[c] = f2bf(xv);
  crow[CH + c] = f2bf(up);
}

// ---------------- FFN2 + LayerNorm + residual, fused ----------------
// A = h1 bf16 [M][512], Bt = w2T bf16 [256][512]; x += LN(A@Bt^T)*g2+b2
__global__ __launch_bounds__(256) void k_ffn2(const unsigned short* __restrict__ A,
                                              const unsigned short* __restrict__ Bt,
                                              const float* __restrict__ g2,
                                              const float* __restrict__ b2,
                                              float* __restrict__ x) {
  constexpr int BM = 64, BN = 256, BK = 64, K = 512;
  __shared__ unsigned short As[BM * BK];
  __shared__ unsigned short Bs[BN * BK];
  __shared__ float sS[2][BM], sQ[2][BM];
  __shared__ float gS[256], bS[256];
  const int tid = threadIdx.x;
  const int lane = tid & 63, w = tid >> 6;
  const int wr = w >> 1, wc = w & 1;
  const int lq = lane & 15, g = lane >> 4;
  const int bm = blockIdx.x * BM;
  gS[tid] = g2[tid]; bS[tid] = b2[tid];
  f32x4 acc[2][8] = {};
  for (int k0 = 0; k0 < K; k0 += BK) {
#pragma unroll
    for (int i = 0; i < 2; ++i) {
      int e = (i * 256 + tid) * 8;
      gload16(A + (size_t)(bm + (e >> 6)) * K + k0 + (e & 63), &As[e]);
    }
#pragma unroll
    for (int i = 0; i < 8; ++i) {
      int e = (i * 256 + tid) * 8;
      gload16(Bt + (size_t)(e >> 6) * K + k0 + (e & 63), &Bs[e]);
    }
    asm volatile("s_waitcnt vmcnt(0)" ::: "memory");
    __syncthreads();
#pragma unroll
    for (int ks = 0; ks < 2; ++ks) {
      bf16x8 a[2], b[8];
#pragma unroll
      for (int m = 0; m < 2; ++m)
        a[m] = *(const bf16x8*)&As[(wr * 32 + m * 16 + lq) * BK + ks * 32 + g * 8];
#pragma unroll
      for (int n = 0; n < 8; ++n)
        b[n] = *(const bf16x8*)&Bs[(wc * 128 + n * 16 + lq) * BK + ks * 32 + g * 8];
#pragma unroll
      for (int m = 0; m < 2; ++m)
#pragma unroll
        for (int n = 0; n < 8; ++n)
          acc[m][n] = __builtin_amdgcn_mfma_f32_16x16x32_bf16(a[m], b[n], acc[m][n], 0, 0, 0);
    }
    __syncthreads();
  }
  // row stats: sum & sumsq over this wave's 128 cols, then combine the two wave-cols
#pragma unroll
  for (int m = 0; m < 2; ++m)
#pragma unroll
    for (int r = 0; r < 4; ++r) {
      float s1 = 0.f, s2 = 0.f;
#pragma unroll
      for (int n = 0; n < 8; ++n) {
        float v = acc[m][n][r];
        s1 += v; s2 += v * v;
      }
#pragma unroll
      for (int d = 1; d < 16; d <<= 1) {
        s1 += __shfl_xor(s1, d);
        s2 += __shfl_xor(s2, d);
      }
      if (lq == 0) {
        int row = wr * 32 + m * 16 + g * 4 + r;
        sS[wc][row] = s1; sQ[wc][row] = s2;
      }
    }
  __syncthreads();
#pragma unroll
  for (int m = 0; m < 2; ++m)
#pragma unroll
    for (int r = 0; r < 4; ++r) {
      int row = wr * 32 + m * 16 + g * 4 + r;
      float mu = (sS[0][row] + sS[1][row]) * (1.f / CH);
      float var = (sQ[0][row] + sQ[1][row]) * (1.f / CH) - mu * mu;
      float rs = rsqrtf(var + 1e-5f);
      size_t gr = (size_t)(bm + row) * CH;
#pragma unroll
      for (int n = 0; n < 8; ++n) {
        int col = wc * 128 + n * 16 + lq;
        float o = (acc[m][n][r] - mu) * rs * gS[col] + bS[col];
        x[gr + col] += o;
      }
    }
}

// ---------------- host-side orchestration ----------------
struct LayerP {
  const float *aggw, *g1, *b1, *g2, *b2;
  const unsigned short *qwT, *kvT, *mwT, *w1T, *w2T;
};

struct Bufs {
  unsigned short *qln, *sln, *msg, *cat, *h1;
  f16 *qh, *kh, *vt;
  float *msg2;
  const float *sinT, *cosT;
};

// attention part for nb batches of tokens (x, src are NHWC feature bases)
static void attn_part(const float* x, const float* src, const LayerP& p, bool rope,
                      int nb, const Bufs& B, hipStream_t stream) {
  const int M = nb * SL;
  k_agg<<<dim3(2 * nb * SL), 256, 0, stream>>>(x, src, p.aggw, p.g1, p.b1, B.qln, B.sln, nb);
  const float* sT = rope ? B.sinT : nullptr;
  const float* cT = rope ? B.cosT : nullptr;
  k_mm<32, 64, 0, 2><<<dim3(M / 32, 4), 256, 0, stream>>>(
      B.qln, p.qwT, B.qh, nullptr, M, CH, CH, sT, cT);
  k_mm<32, 64, 0, 3><<<dim3(M / 32, 8), 256, 0, stream>>>(
      B.sln, p.kvT, B.kh, B.vt, M, CH2, CH, sT, cT);
  k_attn<<<dim3(nb * NHD, 9), 256, 0, stream>>>(B.qh, B.kh, B.vt, B.msg);
  k_mm<32, 64, 0, 0><<<dim3(M / 32, 4), 256, 0, stream>>>(
      B.msg, p.mwT, B.msg2, nullptr, M, CH, CH, nullptr, nullptr);
}

// FFN part for one feature (x is that feature's NHWC base; msg2s its msg2 slice)
static void ffn_part(float* x, const float* msg2s, const LayerP& p,
                     const Bufs& B, hipStream_t stream) {
  k_cat<<<dim3(BSZ * PIX), 256, 0, stream>>>(x, msg2s, B.cat);
  k_mm<128, 128, 1, 1><<<dim3(MFFN / 128, CH2 / 128), 256, 0, stream>>>(
      B.cat, p.w1T, B.h1, nullptr, MFFN, CH2, CH2, nullptr, nullptr);
  k_ffn2<<<dim3(MFFN / 64), 256, 0, stream>>>(B.h1, p.w2T, p.g2, p.b2, x);
}

extern "C" void kernel_launch(void* const* d_in, const int* in_sizes, int n_in,
                              void* d_out, int out_size, void* d_ws, size_t ws_size,
                              hipStream_t stream) {
  const float* in_f0 = (const float*)d_in[0];
  const float* in_f1 = (const float*)d_in[1];
  const float* aggw  = (const float*)d_in[2];
  const float* qw    = (const float*)d_in[3];
  const float* kw    = (const float*)d_in[4];
  const float* vw    = (const float*)d_in[5];
  const float* mw    = (const float*)d_in[6];
  const float* w1    = (const float*)d_in[7];
  const float* w2    = (const float*)d_in[8];
  const float* g1    = (const float*)d_in[9];
  const float* b1    = (const float*)d_in[10];
  const float* g2    = (const float*)d_in[11];
  const float* b2    = (const float*)d_in[12];
  (void)in_sizes; (void)n_in; (void)out_size; (void)ws_size;

  // working feature maps (NHWC) live in d_out (f1 contiguous after f0 -> batched B=4 views work)
  float* f0 = (float*)d_out;
  float* f1 = f0 + FEATN;

  // ---- ws layout (~78 MB) ----
  char* cur = (char*)d_ws;
  auto alloc = [&](size_t bytes) { void* p = cur; cur += (bytes + 255) & ~(size_t)255; return p; };
  float* X = (float*)alloc((size_t)2 * FEATN * 4);          // h1 (bf16) | final staging (f32)
  unsigned short* h1    = (unsigned short*)X;
  float*          stage = X;
  unsigned short* cat  = (unsigned short*)alloc((size_t)MFFN * CH2 * 2);
  unsigned short* qln  = (unsigned short*)alloc((size_t)4 * SL * CH * 2);
  unsigned short* sln  = (unsigned short*)alloc((size_t)4 * SL * CH * 2);
  unsigned short* msg  = (unsigned short*)alloc((size_t)4 * SL * CH * 2);
  float* msg2 = (float*)alloc((size_t)4 * SL * CH * 4);
  f16* qh = (f16*)alloc((size_t)4 * NHD * SL * DHD * 2);
  f16* kh = (f16*)alloc((size_t)4 * NHD * SL * DHD * 2);
  f16* vt = (f16*)alloc((size_t)4 * NHD * SL * DHD * 2);
  float* sinT = (float*)alloc((size_t)SL * CH * 4);
  float* cosT = (float*)alloc((size_t)SL * CH * 4);
  unsigned short* qwT = (unsigned short*)alloc((size_t)8 * CH * CH * 2);
  unsigned short* kvT = (unsigned short*)alloc((size_t)8 * CH2 * CH * 2);
  unsigned short* mwT = (unsigned short*)alloc((size_t)8 * CH * CH * 2);
  unsigned short* w1T = (unsigned short*)alloc((size_t)8 * CH2 * CH2 * 2);
  unsigned short* w2T = (unsigned short*)alloc((size_t)8 * CH * CH2 * 2);

  // init: NCHW -> NHWC, RoPE tables, weight convert+transpose
  k_nchw2nhwc<<<dim3((unsigned)(FEATN / 256)), 256, 0, stream>>>(in_f0, f0);
  k_nchw2nhwc<<<dim3((unsigned)(FEATN / 256)), 256, 0, stream>>>(in_f1, f1);
  k_rope_tables<<<dim3(SL), 256, 0, stream>>>(sinT, cosT);
  k_wt<<<dim3(CH / 32, CH / 32, 8), 256, 0, stream>>>(qw, qwT, CH, CH, (long)CH * CH, (long)CH * CH);
  k_wt<<<dim3(CH / 32, CH / 32, 8), 256, 0, stream>>>(kw, kvT, CH, CH, (long)CH * CH, (long)CH2 * CH);
  k_wt<<<dim3(CH / 32, CH / 32, 8), 256, 0, stream>>>(vw, kvT + (size_t)CH * CH, CH, CH, (long)CH * CH, (long)CH2 * CH);
  k_wt<<<dim3(CH / 32, CH / 32, 8), 256, 0, stream>>>(mw, mwT, CH, CH, (long)CH * CH, (long)CH * CH);
  k_wt<<<dim3(CH2 / 32, CH2 / 32, 8), 256, 0, stream>>>(w1, w1T, CH2, CH2, (long)CH2 * CH2, (long)CH2 * CH2);
  k_wt<<<dim3(CH / 32, CH2 / 32, 8), 256, 0, stream>>>(w2, w2T, CH2, CH, (long)CH2 * CH, (long)CH * CH2);

  Bufs B{qln, sln, msg, cat, h1, qh, kh, vt, msg2, sinT, cosT};

  for (int i = 0; i < 8; ++i) {
    LayerP p{aggw + (long)i * CH * 16,
             g1 + i * CH, b1 + i * CH, g2 + i * CH, b2 + i * CH,
             qwT + (long)i * CH * CH, kvT + (long)i * CH2 * CH,
             mwT + (long)i * CH * CH,
             w1T + (long)i * CH2 * CH2, w2T + (long)i * CH * CH2};
    if ((i & 1) == 0) {
      // self: f0 and f1 independent -> batch attention part with B=4
      attn_part(f0, f0, p, true, 4, B, stream);
      ffn_part(f0, msg2, p, B, stream);
      ffn_part(f1, msg2 + (size_t)2 * SL * CH, p, B, stream);
    } else {
      // cross: sequential (feat1's source is the UPDATED feat0)
      attn_part(f0, f1, p, false, 2, B, stream);
      ffn_part(f0, msg2, p, B, stream);
      attn_part(f1, f0, p, false, 2, B, stream);
      ffn_part(f1, msg2, p, B, stream);
    }
  }

  // final: NHWC -> NCHW via staging, then copy into d_out
  k_nhwc2nchw<<<dim3((unsigned)(FEATN / 256)), 256, 0, stream>>>(f0, stage);
  k_nhwc2nchw<<<dim3((unsigned)(FEATN / 256)), 256, 0, stream>>>(f1, stage + FEATN);
  k_copy<<<dim3((unsigned)(2 * FEATN / 256)), 256, 0, stream>>>(stage, (float*)d_out);
}

// Round 4
// 1536.982 us; speedup vs baseline: 4.0658x; 1.0942x over previous
//
#include <hip/hip_runtime.h>
#include <math.h>

// ---- problem constants ----
constexpr int BSZ = 2;            // batch
constexpr int CH  = 256;          // d_model
constexpr int IH  = 96, IW = 96;  // input H, W
constexpr int HSS = 24, WSS = 24; // aggregated H, W
constexpr int SL  = HSS * WSS;    // 576 tokens
constexpr int NHD = 8, DHD = 32;  // heads, head dim
constexpr int CH2 = 512;          // 2*d_model
constexpr int PIX = IH * IW;      // 9216
constexpr int MFFN = BSZ * PIX;   // 18432
constexpr long FEATN = (long)BSZ * PIX * CH;  // 4,718,592 per feature

typedef __attribute__((ext_vector_type(8))) short bf16x8;
typedef __attribute__((ext_vector_type(4))) float f32x4;
typedef _Float16 f16;
typedef __attribute__((ext_vector_type(8))) _Float16 f16x8;
typedef __attribute__((ext_vector_type(4))) _Float16 f16x4;

__device__ inline unsigned short f2bf(float f) {
  unsigned u = __float_as_uint(f);
  u += 0x7FFFu + ((u >> 16) & 1u);   // RNE
  return (unsigned short)(u >> 16);
}
__device__ inline float bf2f(unsigned short u) {
  return __uint_as_float((unsigned)u << 16);
}

__device__ inline void gload16(const void* g, void* l) {
  __builtin_amdgcn_global_load_lds(
      (const __attribute__((address_space(1))) unsigned int*)g,
      (__attribute__((address_space(3))) unsigned int*)l, 16, 0, 0);
}

// ---------------- block reductions ----------------
__device__ inline float blockSum(float v, float* red) {
  int t = threadIdx.x;
  red[t] = v; __syncthreads();
  for (int s = 128; s > 0; s >>= 1) {
    if (t < s) red[t] += red[t + s];
    __syncthreads();
  }
  float r = red[0]; __syncthreads();
  return r;
}

// ---------------- tiled transposes (coalesced both sides) ----------------
// NCHW f32 -> NHWC f32 + bf16 mirror
__global__ __launch_bounds__(256) void k_in_tr(const float* __restrict__ in,
                                               float* __restrict__ out,
                                               unsigned short* __restrict__ outb) {
  __shared__ float t[32][33];
  const int b = blockIdx.z;
  const int p0 = blockIdx.x * 32, c0 = blockIdx.y * 32;
  const int tx = threadIdx.x & 31, ty = threadIdx.x >> 5;
#pragma unroll
  for (int r = 0; r < 4; ++r)
    t[tx][ty + r * 8] = in[((long)b * CH + c0 + ty + r * 8) * PIX + p0 + tx];
  __syncthreads();
#pragma unroll
  for (int r = 0; r < 4; ++r) {
    float v = t[ty + r * 8][tx];
    long o = ((long)b * PIX + p0 + ty + r * 8) * CH + c0 + tx;
    out[o] = v;
    outb[o] = f2bf(v);
  }
}

// NHWC f32 -> NCHW f32 (directly into d_out)
__global__ __launch_bounds__(256) void k_out_tr(const float* __restrict__ in,
                                                float* __restrict__ out) {
  __shared__ float t[32][33];
  const int b = blockIdx.z;
  const int p0 = blockIdx.x * 32, c0 = blockIdx.y * 32;
  const int tx = threadIdx.x & 31, ty = threadIdx.x >> 5;
#pragma unroll
  for (int r = 0; r < 4; ++r)
    t[ty + r * 8][tx] = in[((long)b * PIX + p0 + ty + r * 8) * CH + c0 + tx];
  __syncthreads();
#pragma unroll
  for (int r = 0; r < 4; ++r)
    out[((long)b * CH + c0 + ty + r * 8) * PIX + p0 + tx] = t[tx][ty + r * 8];
}

// ---------------- weight convert+transpose: W[K][N] f32 -> WT[N][K] bf16 ----------------
__global__ __launch_bounds__(256) void k_wt(const float* __restrict__ W,
                                            unsigned short* __restrict__ WT,
                                            int K, int N, long strideW, long strideT) {
  const long z = blockIdx.z;
  W  += z * strideW;
  WT += z * strideT;
  __shared__ float t[32][33];
  const int n0 = blockIdx.x * 32, k0 = blockIdx.y * 32;
  const int tx = threadIdx.x & 31, ty = threadIdx.x >> 5;
#pragma unroll
  for (int r = 0; r < 4; ++r)
    t[ty + r * 8][tx] = W[(long)(k0 + ty + r * 8) * N + n0 + tx];
  __syncthreads();
#pragma unroll
  for (int r = 0; r < 4; ++r)
    WT[(long)(n0 + ty + r * 8) * K + k0 + tx] = f2bf(t[tx][ty + r * 8]);
}

// ---------------- RoPE tables (24x24 grid) ----------------
__global__ __launch_bounds__(256) void k_rope_tables(float* __restrict__ sinT,
                                                     float* __restrict__ cosT) {
  int l = blockIdx.x;      // 0..575
  int d = threadIdx.x;     // 0..255
  int ii = l / WSS + 1;
  int jj = l % WSS + 1;
  int kidx = d >> 2;
  bool is_i = ((d >> 1) & 1) == 0;
  float div = expf((float)kidx * -0.14391156831212787f);  // -ln(10000)/64
  float pos = is_i ? (float)ii : (float)jj;
  float ang = pos * div;
  sinT[(long)l * CH + d] = sinf(ang);
  cosT[(long)l * CH + d] = cosf(ang);
}

// ---------------- aggregation: depthwise conv / maxpool + LayerNorm -> bf16 ----------------
// reads the bf16 mirror xb
__global__ __launch_bounds__(256) void k_agg(const unsigned short* __restrict__ x,
                                             const unsigned short* __restrict__ src,
                                             const float* __restrict__ aggw,
                                             const float* __restrict__ g,
                                             const float* __restrict__ bt,
                                             unsigned short* __restrict__ qln,
                                             unsigned short* __restrict__ sln,
                                             int nb) {
  int bi = blockIdx.x;
  int mode = 0;
  if (bi >= nb * SL) { mode = 1; bi -= nb * SL; }
  int b = bi / SL, l = bi % SL;
  int i = l / WSS, j = l % WSS;
  int c = threadIdx.x;
  const unsigned short* in = mode ? src : x;   // NHWC bf16
  float v;
  if (mode == 0) {
    v = 0.f;
#pragma unroll
    for (int r = 0; r < 4; ++r)
#pragma unroll
      for (int s = 0; s < 4; ++s)
        v += bf2f(in[(((long)b * IH + i * 4 + r) * IW + j * 4 + s) * CH + c]) *
             aggw[c * 16 + r * 4 + s];
  } else {
    v = -INFINITY;
#pragma unroll
    for (int r = 0; r < 4; ++r)
#pragma unroll
      for (int s = 0; s < 4; ++s)
        v = fmaxf(v, bf2f(in[(((long)b * IH + i * 4 + r) * IW + j * 4 + s) * CH + c]));
  }
  __shared__ float red[256];
  float mu = blockSum(v, red) * (1.f / CH);
  float dv = v - mu;
  float var = blockSum(dv * dv, red) * (1.f / CH);
  float o = dv * rsqrtf(var + 1e-5f) * g[c] + bt[c];
  (mode ? sln : qln)[(long)(b * SL + l) * CH + c] = f2bf(o);
}

// ---------------- bf16 MFMA GEMM: C = A @ Bt^T ----------------
// OUT: 0 f32 C0[row*ldc+col]; 1 bf16 C0[row*ldc+col];
//      4 QKV-mode: col>>8 selects {Q->C0 (rope+scale), K->C1 (rope), V->C2 (transposed)}
//        A used for col<256 (qln), A2 for col>=256 (sln).
template <int BM, int BN, int OUT>
__global__ __launch_bounds__(256) void k_mm(const unsigned short* __restrict__ A,
                                            const unsigned short* __restrict__ A2,
                                            const unsigned short* __restrict__ Bt,
                                            void* __restrict__ C0, void* __restrict__ C1,
                                            void* __restrict__ C2,
                                            int M, int K, int lda, int ldb, int koff, int ldc,
                                            const float* __restrict__ sinT,
                                            const float* __restrict__ cosT) {
  constexpr int BK = 64;
  constexpr int WM = BM / 2, WN = BN / 2;      // 2x2 waves
  constexpr int FM = WM / 16, FN = WN / 16;
  __shared__ unsigned short As[BM * BK];
  __shared__ unsigned short Bs[BN * BK];
  const int tid = threadIdx.x;
  const int lane = tid & 63, w = tid >> 6;
  const int wr = w >> 1, wc = w & 1;
  const int lq = lane & 15, g = lane >> 4;
  const int bm = blockIdx.x * BM, bn = blockIdx.y * BN;
  const unsigned short* Ause = (OUT == 4 && bn >= CH) ? A2 : A;

  f32x4 acc[FM][FN] = {};
  for (int k0 = 0; k0 < K; k0 += BK) {
    constexpr int RA = BM * BK / 2048;
#pragma unroll
    for (int i = 0; i < RA; ++i) {
      int e = (i * 256 + tid) * 8;
      gload16(Ause + (size_t)(bm + (e >> 6)) * lda + k0 + (e & 63), &As[e]);
    }
    constexpr int RB = BN * BK / 2048;
#pragma unroll
    for (int i = 0; i < RB; ++i) {
      int e = (i * 256 + tid) * 8;
      gload16(Bt + (size_t)(bn + (e >> 6)) * ldb + koff + k0 + (e & 63), &Bs[e]);
    }
    asm volatile("s_waitcnt vmcnt(0)" ::: "memory");
    __syncthreads();
#pragma unroll
    for (int ks = 0; ks < 2; ++ks) {
      bf16x8 a[FM], b[FN];
#pragma unroll
      for (int m = 0; m < FM; ++m)
        a[m] = *(const bf16x8*)&As[(wr * WM + m * 16 + lq) * BK + ks * 32 + g * 8];
#pragma unroll
      for (int n = 0; n < FN; ++n)
        b[n] = *(const bf16x8*)&Bs[(wc * WN + n * 16 + lq) * BK + ks * 32 + g * 8];
#pragma unroll
      for (int m = 0; m < FM; ++m)
#pragma unroll
        for (int n = 0; n < FN; ++n)
          acc[m][n] = __builtin_amdgcn_mfma_f32_16x16x32_bf16(a[m], b[n], acc[m][n], 0, 0, 0);
    }
    __syncthreads();
  }
  // D layout: col = lane&15 (B index), row = (lane>>4)*4 + r (A index)
#pragma unroll
  for (int m = 0; m < FM; ++m) {
    const int rowb = bm + wr * WM + m * 16 + g * 4;
#pragma unroll
    for (int n = 0; n < FN; ++n) {
      const int col = bn + wc * WN + n * 16 + lq;
#pragma unroll
      for (int r = 0; r < 4; ++r) {
        const int row = rowb + r;
        float v = acc[m][n][r];
        if (OUT == 0) {
          ((float*)C0)[(size_t)row * ldc + col] = v;
        } else if (OUT == 1) {
          ((unsigned short*)C0)[(size_t)row * ldc + col] = f2bf(v);
        } else {  // OUT == 4
          const int b = row / SL, s = row - b * SL;
          const int which = col >> 8;     // 0=Q,1=K,2=V
          const int ch = col & 255;
          float vp = __shfl_xor(v, 1);    // partner channel (ch^1)
          if (which < 2 && sinT) {
            float sn = sinT[(size_t)s * CH + ch];
            float cs = cosT[(size_t)s * CH + ch];
            v = ((lane & 1) == 0) ? v * cs - vp * sn : v * cs + vp * sn;
          }
          if (which == 0) v *= 0.17677669529663687f;  // 1/sqrt(32) folded into Q
          const int h = ch >> 5, d = ch & 31;
          if (which == 0)
            ((f16*)C0)[(((size_t)b * NHD + h) * SL + s) * DHD + d] = (f16)v;
          else if (which == 1)
            ((f16*)C1)[(((size_t)b * NHD + h) * SL + s) * DHD + d] = (f16)v;
          else
            ((f16*)C2)[(((size_t)b * NHD + h) * DHD + d) * SL + s] = (f16)v;
        }
      }
    }
  }
}

// ---------------- fused flash attention ----------------
// qh,kh: f16 [bh][576][32]; vt: f16 [bh][32][576]; msgA: bf16 [token][256]
// grid (nb*8, 36), block 64 (one wave = 16 q-rows).
__global__ __launch_bounds__(64) void k_attn(const f16* __restrict__ qh,
                                             const f16* __restrict__ kh,
                                             const f16* __restrict__ vt,
                                             unsigned short* __restrict__ msgA) {
  const int bh = blockIdx.x;
  const int b = bh >> 3, h = bh & 7;
  const int lane = threadIdx.x;
  const int lq = lane & 15, g = lane >> 4;
  const int q0 = blockIdx.y * 16;

  const f16x8 qf = *(const f16x8*)&qh[((size_t)bh * SL + q0 + lq) * DHD + g * 8];
  const f16* kbase = kh + (size_t)bh * SL * DHD;
  const f16* vbase = vt + (size_t)bh * DHD * SL;

  f32x4 o0 = {}, o1 = {};          // O^T[d][q]: d-tiles 0-15, 16-31; col q = lq
  float m = -1e30f, l = 0.f;
  for (int t = 0; t < 36; ++t) {
    // S^T tile: mfma(A=K rows, B=Q rows) -> col=q=lq, row = s = t*16 + g*4 + r
    f16x8 kf = *(const f16x8*)&kbase[((size_t)(t * 16 + lq)) * DHD + g * 8];
    f32x4 s = __builtin_amdgcn_mfma_f32_16x16x32_f16(kf, qf, (f32x4){0.f, 0.f, 0.f, 0.f}, 0, 0, 0);
    float tm = fmaxf(fmaxf(s[0], s[1]), fmaxf(s[2], s[3]));
    tm = fmaxf(tm, __shfl_xor(tm, 16));
    tm = fmaxf(tm, __shfl_xor(tm, 32));   // all 4 groups share per-q tile max
    if (__any(tm > m + 5.f)) {            // deferred-max rescale (THR=5)
      float mn = fmaxf(m, tm);
      float f = __expf(m - mn);
      o0 *= f; o1 *= f; l *= f; m = mn;
    }
    float e0 = __expf(s[0] - m), e1 = __expf(s[1] - m);
    float e2 = __expf(s[2] - m), e3 = __expf(s[3] - m);
    l += (e0 + e1) + (e2 + e3);
    f16x4 ef = {(f16)e0, (f16)e1, (f16)e2, (f16)e3};  // B-frag: n=q=lq, k=g*4+r
    f16x4 va = *(const f16x4*)&vbase[(size_t)lq * SL + t * 16 + g * 4];
    f16x4 vb = *(const f16x4*)&vbase[(size_t)(16 + lq) * SL + t * 16 + g * 4];
    o0 = __builtin_amdgcn_mfma_f32_16x16x16f16(va, ef, o0, 0, 0, 0);
    o1 = __builtin_amdgcn_mfma_f32_16x16x16f16(vb, ef, o1, 0, 0, 0);
  }
  l += __shfl_xor(l, 16);
  l += __shfl_xor(l, 32);
  float inv = 1.f / l;
  unsigned short* mrow = msgA + ((size_t)(b * SL + q0 + lq)) * CH + h * DHD;
#pragma unroll
  for (int mt = 0; mt < 2; ++mt) {
    f32x4 o = mt ? o1 : o0;
    unsigned a0 = f2bf(o[0] * inv) | ((unsigned)f2bf(o[1] * inv) << 16);
    unsigned a1 = f2bf(o[2] * inv) | ((unsigned)f2bf(o[3] * inv) << 16);
    uint2 u; u.x = a0; u.y = a1;
    *(uint2*)&mrow[mt * 16 + g * 4] = u;
  }
}

// ---------------- FFN1: h1 = LeakyReLU(xb @ w1_top + interp(Z)) ----------------
// xb bf16 [MFFN][256]; w1T bf16 [512][512] (use k 0..255); Z f32 [2*SL][512] (this feature)
__global__ __launch_bounds__(256) void k_ffn1(const unsigned short* __restrict__ xb,
                                              const unsigned short* __restrict__ w1T,
                                              const float* __restrict__ Z,
                                              unsigned short* __restrict__ h1) {
  constexpr int BM = 128, BN = 128, BK = 64, K = 256;
  constexpr int WM = 64, WN = 64, FM = 4, FN = 4;
  __shared__ unsigned short As[BM * BK];
  __shared__ unsigned short Bs[BN * BK];
  const int tid = threadIdx.x;
  const int lane = tid & 63, w = tid >> 6;
  const int wr = w >> 1, wc = w & 1;
  const int lq = lane & 15, g = lane >> 4;
  const int bm = blockIdx.x * BM, bn = blockIdx.y * BN;

  f32x4 acc[FM][FN] = {};
  for (int k0 = 0; k0 < K; k0 += BK) {
#pragma unroll
    for (int i = 0; i < 4; ++i) {
      int e = (i * 256 + tid) * 8;
      gload16(xb + (size_t)(bm + (e >> 6)) * 256 + k0 + (e & 63), &As[e]);
    }
#pragma unroll
    for (int i = 0; i < 4; ++i) {
      int e = (i * 256 + tid) * 8;
      gload16(w1T + (size_t)(bn + (e >> 6)) * 512 + k0 + (e & 63), &Bs[e]);
    }
    asm volatile("s_waitcnt vmcnt(0)" ::: "memory");
    __syncthreads();
#pragma unroll
    for (int ks = 0; ks < 2; ++ks) {
      bf16x8 a[FM], b[FN];
#pragma unroll
      for (int m = 0; m < FM; ++m)
        a[m] = *(const bf16x8*)&As[(wr * WM + m * 16 + lq) * BK + ks * 32 + g * 8];
#pragma unroll
      for (int n = 0; n < FN; ++n)
        b[n] = *(const bf16x8*)&Bs[(wc * WN + n * 16 + lq) * BK + ks * 32 + g * 8];
#pragma unroll
      for (int m = 0; m < FM; ++m)
#pragma unroll
        for (int n = 0; n < FN; ++n)
          acc[m][n] = __builtin_amdgcn_mfma_f32_16x16x32_bf16(a[m], b[n], acc[m][n], 0, 0, 0);
    }
    __syncthreads();
  }
#pragma unroll
  for (int m = 0; m < FM; ++m) {
    const int rowb = bm + wr * WM + m * 16 + g * 4;
#pragma unroll
    for (int r = 0; r < 4; ++r) {
      const int row = rowb + r;
      const int b = row >= PIX;
      const int p = row - b * PIX;
      const int y = p / IW, xx = p - y * IW;
      float sy = (y + 0.5f) * 0.25f - 0.5f;
      float sx = (xx + 0.5f) * 0.25f - 0.5f;
      int y0 = (int)floorf(sy); float wy = sy - y0;
      int x0 = (int)floorf(sx); float wx = sx - x0;
      int y1 = min(y0 + 1, HSS - 1); y0 = max(y0, 0);
      int x1 = min(x0 + 1, WSS - 1); x0 = max(x0, 0);
      const float* Zb = Z + (size_t)b * SL * CH2;
      const float* z00 = Zb + (size_t)(y0 * WSS + x0) * CH2;
      const float* z01 = Zb + (size_t)(y0 * WSS + x1) * CH2;
      const float* z10 = Zb + (size_t)(y1 * WSS + x0) * CH2;
      const float* z11 = Zb + (size_t)(y1 * WSS + x1) * CH2;
      float w00 = (1.f - wy) * (1.f - wx), w01 = (1.f - wy) * wx;
      float w10 = wy * (1.f - wx), w11 = wy * wx;
#pragma unroll
      for (int n = 0; n < FN; ++n) {
        const int col = bn + wc * WN + n * 16 + lq;
        float v = acc[m][n][r] + w00 * z00[col] + w01 * z01[col] +
                  w10 * z10[col] + w11 * z11[col];
        v = v >= 0.f ? v : 0.01f * v;
        h1[(size_t)row * CH2 + col] = f2bf(v);
      }
    }
  }
}

// ---------------- FFN2 + LayerNorm + residual (also refresh bf16 mirror) ----------------
__global__ __launch_bounds__(256) void k_ffn2(const unsigned short* __restrict__ A,
                                              const unsigned short* __restrict__ Bt,
                                              const float* __restrict__ g2,
                                              const float* __restrict__ b2,
                                              float* __restrict__ x,
                                              unsigned short* __restrict__ xb) {
  constexpr int BM = 64, BN = 256, BK = 64, K = 512;
  __shared__ unsigned short As[BM * BK];
  __shared__ unsigned short Bs[BN * BK];
  __shared__ float sS[2][BM], sQ[2][BM];
  __shared__ float gS[256], bS[256];
  const int tid = threadIdx.x;
  const int lane = tid & 63, w = tid >> 6;
  const int wr = w >> 1, wc = w & 1;
  const int lq = lane & 15, g = lane >> 4;
  const int bm = blockIdx.x * BM;
  gS[tid] = g2[tid]; bS[tid] = b2[tid];
  f32x4 acc[2][8] = {};
  for (int k0 = 0; k0 < K; k0 += BK) {
#pragma unroll
    for (int i = 0; i < 2; ++i) {
      int e = (i * 256 + tid) * 8;
      gload16(A + (size_t)(bm + (e >> 6)) * K + k0 + (e & 63), &As[e]);
    }
#pragma unroll
    for (int i = 0; i < 8; ++i) {
      int e = (i * 256 + tid) * 8;
      gload16(Bt + (size_t)(e >> 6) * K + k0 + (e & 63), &Bs[e]);
    }
    asm volatile("s_waitcnt vmcnt(0)" ::: "memory");
    __syncthreads();
#pragma unroll
    for (int ks = 0; ks < 2; ++ks) {
      bf16x8 a[2], b[8];
#pragma unroll
      for (int m = 0; m < 2; ++m)
        a[m] = *(const bf16x8*)&As[(wr * 32 + m * 16 + lq) * BK + ks * 32 + g * 8];
#pragma unroll
      for (int n = 0; n < 8; ++n)
        b[n] = *(const bf16x8*)&Bs[(wc * 128 + n * 16 + lq) * BK + ks * 32 + g * 8];
#pragma unroll
      for (int m = 0; m < 2; ++m)
#pragma unroll
        for (int n = 0; n < 8; ++n)
          acc[m][n] = __builtin_amdgcn_mfma_f32_16x16x32_bf16(a[m], b[n], acc[m][n], 0, 0, 0);
    }
    __syncthreads();
  }
#pragma unroll
  for (int m = 0; m < 2; ++m)
#pragma unroll
    for (int r = 0; r < 4; ++r) {
      float s1 = 0.f, s2 = 0.f;
#pragma unroll
      for (int n = 0; n < 8; ++n) {
        float v = acc[m][n][r];
        s1 += v; s2 += v * v;
      }
#pragma unroll
      for (int d = 1; d < 16; d <<= 1) {
        s1 += __shfl_xor(s1, d);
        s2 += __shfl_xor(s2, d);
      }
      if (lq == 0) {
        int row = wr * 32 + m * 16 + g * 4 + r;
        sS[wc][row] = s1; sQ[wc][row] = s2;
      }
    }
  __syncthreads();
#pragma unroll
  for (int m = 0; m < 2; ++m)
#pragma unroll
    for (int r = 0; r < 4; ++r) {
      int row = wr * 32 + m * 16 + g * 4 + r;
      float mu = (sS[0][row] + sS[1][row]) * (1.f / CH);
      float var = (sQ[0][row] + sQ[1][row]) * (1.f / CH) - mu * mu;
      float rs = rsqrtf(var + 1e-5f);
      size_t gr = (size_t)(bm + row) * CH;
#pragma unroll
      for (int n = 0; n < 8; ++n) {
        int col = wc * 128 + n * 16 + lq;
        float o = (acc[m][n][r] - mu) * rs * gS[col] + bS[col];
        float nx = x[gr + col] + o;
        x[gr + col] = nx;
        xb[gr + col] = f2bf(nx);
      }
    }
}

// ---------------- host-side orchestration ----------------
struct LayerP {
  const float *aggw, *g1, *b1, *g2, *b2;
  const unsigned short *qkvT, *mwT, *w1T, *w2T;
};

struct Bufs {
  unsigned short *qln, *sln, *msgA, *msgb, *h1, *xb;
  f16 *qh, *kh, *vt;
  float *Zbuf, *f;
  const float *sinT, *cosT;
};

// attention part: agg + QKV proj + flash attn + merge + Z GEMM (nb batches of tokens)
static void attn_part(long xoff, long soff, const LayerP& p, bool rope, int nb,
                      const Bufs& B, hipStream_t stream) {
  const int M = nb * SL;
  k_agg<<<dim3(2 * nb * SL), 256, 0, stream>>>(B.xb + xoff, B.xb + soff, p.aggw,
                                               p.g1, p.b1, B.qln, B.sln, nb);
  const float* sT = rope ? B.sinT : nullptr;
  const float* cT = rope ? B.cosT : nullptr;
  k_mm<32, 64, 4><<<dim3(M / 32, 12), 256, 0, stream>>>(
      B.qln, B.sln, p.qkvT, B.qh, B.kh, B.vt, M, CH, CH, CH, 0, 0, sT, cT);
  k_attn<<<dim3(nb * NHD, 36), 64, 0, stream>>>(B.qh, B.kh, B.vt, B.msgA);
  k_mm<32, 64, 1><<<dim3(M / 32, 4), 256, 0, stream>>>(
      B.msgA, nullptr, p.mwT, B.msgb, nullptr, nullptr, M, CH, CH, CH, 0, CH, nullptr, nullptr);
  // Z = msgb @ w1_bot^T  (exploits linearity of bilinear upsample)
  k_mm<64, 64, 0><<<dim3(M / 64, 8), 256, 0, stream>>>(
      B.msgb, nullptr, p.w1T, B.Zbuf, nullptr, nullptr, M, CH, CH, CH2, CH, CH2, nullptr, nullptr);
}

static void ffn_part(int fi, const float* Zs, const LayerP& p, const Bufs& B,
                     hipStream_t stream) {
  k_ffn1<<<dim3(MFFN / 128, 4), 256, 0, stream>>>(B.xb + (long)fi * FEATN, p.w1T, Zs, B.h1);
  k_ffn2<<<dim3(MFFN / 64), 256, 0, stream>>>(B.h1, p.w2T, p.g2, p.b2,
                                              B.f + (long)fi * FEATN, B.xb + (long)fi * FEATN);
}

extern "C" void kernel_launch(void* const* d_in, const int* in_sizes, int n_in,
                              void* d_out, int out_size, void* d_ws, size_t ws_size,
                              hipStream_t stream) {
  const float* in_f0 = (const float*)d_in[0];
  const float* in_f1 = (const float*)d_in[1];
  const float* aggw  = (const float*)d_in[2];
  const float* qw    = (const float*)d_in[3];
  const float* kw    = (const float*)d_in[4];
  const float* vw    = (const float*)d_in[5];
  const float* mw    = (const float*)d_in[6];
  const float* w1    = (const float*)d_in[7];
  const float* w2    = (const float*)d_in[8];
  const float* g1    = (const float*)d_in[9];
  const float* b1    = (const float*)d_in[10];
  const float* g2    = (const float*)d_in[11];
  const float* b2    = (const float*)d_in[12];
  (void)in_sizes; (void)n_in; (void)out_size; (void)ws_size;

  // ---- ws layout (~100 MB; ws is ~268 MB per the poison-fill WRITE_SIZE) ----
  char* cur = (char*)d_ws;
  auto alloc = [&](size_t bytes) { void* p = cur; cur += (bytes + 255) & ~(size_t)255; return p; };
  float*          f    = (float*)alloc((size_t)2 * FEATN * 4);           // NHWC features f32
  unsigned short* xb   = (unsigned short*)alloc((size_t)2 * FEATN * 2);  // bf16 mirror
  unsigned short* h1   = (unsigned short*)alloc((size_t)MFFN * CH2 * 2);
  float*          Zbuf = (float*)alloc((size_t)4 * SL * CH2 * 4);
  unsigned short* msgA = (unsigned short*)alloc((size_t)4 * SL * CH * 2);
  unsigned short* msgb = (unsigned short*)alloc((size_t)4 * SL * CH * 2);
  unsigned short* qln  = (unsigned short*)alloc((size_t)4 * SL * CH * 2);
  unsigned short* sln  = (unsigned short*)alloc((size_t)4 * SL * CH * 2);
  f16* qh = (f16*)alloc((size_t)4 * NHD * SL * DHD * 2);
  f16* kh = (f16*)alloc((size_t)4 * NHD * SL * DHD * 2);
  f16* vt = (f16*)alloc((size_t)4 * NHD * SL * DHD * 2);
  float* sinT = (float*)alloc((size_t)SL * CH * 4);
  float* cosT = (float*)alloc((size_t)SL * CH * 4);
  unsigned short* qkvT = (unsigned short*)alloc((size_t)8 * 3 * CH * CH * 2);  // [768][256] per layer
  unsigned short* mwT  = (unsigned short*)alloc((size_t)8 * CH * CH * 2);
  unsigned short* w1T  = (unsigned short*)alloc((size_t)8 * CH2 * CH2 * 2);    // [512][512]
  unsigned short* w2T  = (unsigned short*)alloc((size_t)8 * CH * CH2 * 2);     // [256][512]

  // init: NCHW -> NHWC (+bf16 mirror), RoPE tables, weight transposes
  k_in_tr<<<dim3(PIX / 32, CH / 32, BSZ), 256, 0, stream>>>(in_f0, f, xb);
  k_in_tr<<<dim3(PIX / 32, CH / 32, BSZ), 256, 0, stream>>>(in_f1, f + FEATN, xb + FEATN);
  k_rope_tables<<<dim3(SL), 256, 0, stream>>>(sinT, cosT);
  k_wt<<<dim3(CH / 32, CH / 32, 8), 256, 0, stream>>>(qw, qkvT, CH, CH, (long)CH * CH, (long)3 * CH * CH);
  k_wt<<<dim3(CH / 32, CH / 32, 8), 256, 0, stream>>>(kw, qkvT + (size_t)CH * CH, CH, CH, (long)CH * CH, (long)3 * CH * CH);
  k_wt<<<dim3(CH / 32, CH / 32, 8), 256, 0, stream>>>(vw, qkvT + (size_t)2 * CH * CH, CH, CH, (long)CH * CH, (long)3 * CH * CH);
  k_wt<<<dim3(CH / 32, CH / 32, 8), 256, 0, stream>>>(mw, mwT, CH, CH, (long)CH * CH, (long)CH * CH);
  k_wt<<<dim3(CH2 / 32, CH2 / 32, 8), 256, 0, stream>>>(w1, w1T, CH2, CH2, (long)CH2 * CH2, (long)CH2 * CH2);
  k_wt<<<dim3(CH / 32, CH2 / 32, 8), 256, 0, stream>>>(w2, w2T, CH2, CH, (long)CH2 * CH, (long)CH * CH2);

  Bufs B{qln, sln, msgA, msgb, h1, xb, qh, kh, vt, Zbuf, f, sinT, cosT};

  for (int i = 0; i < 8; ++i) {
    LayerP p{aggw + (long)i * CH * 16,
             g1 + i * CH, b1 + i * CH, g2 + i * CH, b2 + i * CH,
             qkvT + (long)i * 3 * CH * CH, mwT + (long)i * CH * CH,
             w1T + (long)i * CH2 * CH2, w2T + (long)i * CH * CH2};
    if ((i & 1) == 0) {
      // self: f0 and f1 independent -> batch attention with nb=4 (xb is contiguous)
      attn_part(0, 0, p, true, 4, B, stream);
      ffn_part(0, Zbuf, p, B, stream);
      ffn_part(1, Zbuf + (size_t)2 * SL * CH2, p, B, stream);
    } else {
      // cross: sequential (feat1's source is the UPDATED feat0)
      attn_part(0, FEATN, p, false, 2, B, stream);
      ffn_part(0, Zbuf, p, B, stream);
      attn_part(FEATN, 0, p, false, 2, B, stream);
      ffn_part(1, Zbuf, p, B, stream);
    }
  }

  // final: NHWC -> NCHW directly into d_out
  float* outp = (float*)d_out;
  k_out_tr<<<dim3(PIX / 32, CH / 32, BSZ), 256, 0, stream>>>(f, outp);
  k_out_tr<<<dim3(PIX / 32, CH / 32, BSZ), 256, 0, stream>>>(f + FEATN, outp + FEATN);
}

// Round 5
// 1272.703 us; speedup vs baseline: 4.9101x; 1.2077x over previous
//
#include <hip/hip_runtime.h>
#include <math.h>

// ---- problem constants ----
constexpr int BSZ = 2;            // batch
constexpr int CH  = 256;          // d_model
constexpr int IH  = 96, IW = 96;  // input H, W
constexpr int HSS = 24, WSS = 24; // aggregated H, W
constexpr int SL  = HSS * WSS;    // 576 tokens
constexpr int NHD = 8, DHD = 32;  // heads, head dim
constexpr int CH2 = 512;          // 2*d_model
constexpr int PIX = IH * IW;      // 9216
constexpr int MFFN = BSZ * PIX;   // 18432
constexpr long FEATN = (long)BSZ * PIX * CH;  // 4,718,592 per feature

typedef __attribute__((ext_vector_type(8))) short bf16x8;
typedef __attribute__((ext_vector_type(4))) float f32x4;
typedef _Float16 f16;
typedef __attribute__((ext_vector_type(8))) _Float16 f16x8;
typedef __attribute__((ext_vector_type(4))) _Float16 f16x4;

// Swizzle convention: every bf16 tensor consumed as a GEMM operand is STORED
// with element column  k' = k ^ ((row & 7) << 3)  (XOR inside each aligned
// 64-element chunk of the K dim). global_load_lds stages it linearly; the
// fragment read applies the same XOR -> bank-conflict-free ds_read_b128.

__device__ inline unsigned short f2bf(float f) {
  unsigned u = __float_as_uint(f);
  u += 0x7FFFu + ((u >> 16) & 1u);   // RNE
  return (unsigned short)(u >> 16);
}
__device__ inline float bf2f(unsigned short u) {
  return __uint_as_float((unsigned)u << 16);
}

__device__ inline void gload16(const void* g, void* l) {
  __builtin_amdgcn_global_load_lds(
      (const __attribute__((address_space(1))) unsigned int*)g,
      (__attribute__((address_space(3))) unsigned int*)l, 16, 0, 0);
}

// ---------------- tiled transposes ----------------
// NCHW f32 -> NHWC f32 master + swizzled bf16 mirror
__global__ __launch_bounds__(256) void k_in_tr(const float* __restrict__ in,
                                               float* __restrict__ out,
                                               unsigned short* __restrict__ outb) {
  __shared__ float t[32][33];
  const int b = blockIdx.z;
  const int p0 = blockIdx.x * 32, c0 = blockIdx.y * 32;
  const int tx = threadIdx.x & 31, ty = threadIdx.x >> 5;
#pragma unroll
  for (int r = 0; r < 4; ++r)
    t[tx][ty + r * 8] = in[((long)b * CH + c0 + ty + r * 8) * PIX + p0 + tx];
  __syncthreads();
#pragma unroll
  for (int r = 0; r < 4; ++r) {
    float v = t[ty + r * 8][tx];
    long row = (long)b * PIX + p0 + ty + r * 8;         // row & 7 == ty
    out[row * CH + c0 + tx] = v;
    outb[row * CH + ((c0 + tx) ^ (ty << 3))] = f2bf(v);
  }
}

// NHWC f32 -> NCHW f32 (into d_out)
__global__ __launch_bounds__(256) void k_out_tr(const float* __restrict__ in,
                                                float* __restrict__ out) {
  __shared__ float t[32][33];
  const int b = blockIdx.z;
  const int p0 = blockIdx.x * 32, c0 = blockIdx.y * 32;
  const int tx = threadIdx.x & 31, ty = threadIdx.x >> 5;
#pragma unroll
  for (int r = 0; r < 4; ++r)
    t[ty + r * 8][tx] = in[((long)b * PIX + p0 + ty + r * 8) * CH + c0 + tx];
  __syncthreads();
#pragma unroll
  for (int r = 0; r < 4; ++r)
    out[((long)b * CH + c0 + ty + r * 8) * PIX + p0 + tx] = t[tx][ty + r * 8];
}

// ---------------- weight convert+transpose: W[K][N] f32 -> WT[N][K] bf16 (swizzled) ----------------
__global__ __launch_bounds__(256) void k_wt(const float* __restrict__ W,
                                            unsigned short* __restrict__ WT,
                                            int K, int N, long strideW, long strideT) {
  const long z = blockIdx.z;
  W  += z * strideW;
  WT += z * strideT;
  __shared__ float t[32][33];
  const int n0 = blockIdx.x * 32, k0 = blockIdx.y * 32;
  const int tx = threadIdx.x & 31, ty = threadIdx.x >> 5;
#pragma unroll
  for (int r = 0; r < 4; ++r)
    t[ty + r * 8][tx] = W[(long)(k0 + ty + r * 8) * N + n0 + tx];
  __syncthreads();
#pragma unroll
  for (int r = 0; r < 4; ++r) {
    int n = n0 + ty + r * 8;
    WT[(long)n * K + ((k0 + tx) ^ ((n & 7) << 3))] = f2bf(t[tx][ty + r * 8]);
  }
}

// straight f32 -> bf16 convert (swizzled rows), batched over layers: mw -> mwB
__global__ __launch_bounds__(256) void k_cvt(const float* __restrict__ W,
                                             unsigned short* __restrict__ O) {
  const int i = blockIdx.x;             // row (in-ch)
  const long z = blockIdx.y;
  const int k = threadIdx.x;
  O[(z * CH + i) * CH + (k ^ ((i & 7) << 3))] = f2bf(W[(z * CH + i) * CH + k]);
}

// ---------------- RoPE tables (24x24 grid) ----------------
__global__ __launch_bounds__(256) void k_rope_tables(float* __restrict__ sinT,
                                                     float* __restrict__ cosT) {
  int l = blockIdx.x;      // 0..575
  int d = threadIdx.x;     // 0..255
  int ii = l / WSS + 1;
  int jj = l % WSS + 1;
  int kidx = d >> 2;
  bool is_i = ((d >> 1) & 1) == 0;
  float div = expf((float)kidx * -0.14391156831212787f);  // -ln(10000)/64
  float pos = is_i ? (float)ii : (float)jj;
  float ang = pos * div;
  sinT[(long)l * CH + d] = sinf(ang);
  cosT[(long)l * CH + d] = cosf(ang);
}

// ---------------- aggregation: depthwise conv / maxpool + LayerNorm -> bf16 (swizzled) ----------------
__global__ __launch_bounds__(256) void k_agg(const unsigned short* __restrict__ x,
                                             const unsigned short* __restrict__ src,
                                             const float* __restrict__ aggw,
                                             const float* __restrict__ g,
                                             const float* __restrict__ bt,
                                             unsigned short* __restrict__ qln,
                                             unsigned short* __restrict__ sln,
                                             int nb) {
  int bi = blockIdx.x;
  int mode = 0;
  if (bi >= nb * SL) { mode = 1; bi -= nb * SL; }
  int b = bi / SL, l = bi % SL;
  int i = l / WSS, j = l % WSS;
  int c = threadIdx.x;
  const unsigned short* in = mode ? src : x;   // NHWC bf16 swizzled
  float v;
  if (mode == 0) {
    v = 0.f;
#pragma unroll
    for (int r = 0; r < 4; ++r)
#pragma unroll
      for (int s = 0; s < 4; ++s)
        v += bf2f(in[(((long)b * IH + i * 4 + r) * IW + j * 4 + s) * CH +
                     (c ^ (((j * 4 + s) & 7) << 3))]) *
             aggw[c * 16 + r * 4 + s];
  } else {
    v = -INFINITY;
#pragma unroll
    for (int r = 0; r < 4; ++r)
#pragma unroll
      for (int s = 0; s < 4; ++s)
        v = fmaxf(v, bf2f(in[(((long)b * IH + i * 4 + r) * IW + j * 4 + s) * CH +
                             (c ^ (((j * 4 + s) & 7) << 3))]));
  }
  __shared__ float red[8];
  float s1 = v, s2 = v * v;
#pragma unroll
  for (int d = 1; d < 64; d <<= 1) { s1 += __shfl_xor(s1, d); s2 += __shfl_xor(s2, d); }
  int wv = threadIdx.x >> 6;
  if ((threadIdx.x & 63) == 0) { red[wv * 2] = s1; red[wv * 2 + 1] = s2; }
  __syncthreads();
  s1 = red[0] + red[2] + red[4] + red[6];
  s2 = red[1] + red[3] + red[5] + red[7];
  float mu = s1 * (1.f / CH);
  float var = s2 * (1.f / CH) - mu * mu;
  float o = (v - mu) * rsqrtf(var + 1e-5f) * g[c] + bt[c];
  (mode ? sln : qln)[(long)(b * SL + l) * CH + (c ^ ((l & 7) << 3))] = f2bf(o);
}

// ---------------- pipelined bf16 MFMA GEMM: C = A @ Bt^T ----------------
// All A/Bt stored swizzled. 2-phase double-buffered staging.
// OUT: 0 f32 C0[row*ldc+col]; 5 bf16 swizzled (for future use as B);
//      4 QKV: col>>8 {0:Q->C0 (rope+scale), 1:K->C1 (rope), 2:V->C2 transposed}, A2 for col>=256
template <int BM, int BN, int OUT>
__global__ __launch_bounds__(256) void k_mm(const unsigned short* __restrict__ A,
                                            const unsigned short* __restrict__ A2,
                                            const unsigned short* __restrict__ Bt,
                                            void* __restrict__ C0, void* __restrict__ C1,
                                            void* __restrict__ C2,
                                            int M, int K, int lda, int ldb,
                                            int koffA, int koffB, int ldc,
                                            const float* __restrict__ sinT,
                                            const float* __restrict__ cosT,
                                            long zsA, long zsB, long zsC) {
  constexpr int BK = 64;
  constexpr int WM = BM / 2, WN = BN / 2;
  constexpr int FM = WM / 16, FN = WN / 16;
  constexpr int RA = BM * BK / 2048, RB = BN * BK / 2048;
  __shared__ unsigned short As[2][BM * BK];
  __shared__ unsigned short Bs[2][BN * BK];
  const int tid = threadIdx.x;
  const int lane = tid & 63, w = tid >> 6;
  const int wr = w >> 1, wc = w & 1;
  const int lq = lane & 15, g = lane >> 4;
  const int sw = (lq & 7) << 3;
  const int bm = blockIdx.x * BM, bn = blockIdx.y * BN;
  const long z = blockIdx.z;
  const unsigned short* Ap = ((OUT == 4 && bn >= CH) ? A2 : A) + z * zsA + koffA;
  const unsigned short* Bp = Bt + z * zsB + koffB;

  auto stA = [&](int buf, int k0) {
#pragma unroll
    for (int i = 0; i < RA; ++i) {
      int e = (i * 256 + tid) * 8;
      gload16(Ap + (size_t)(bm + (e >> 6)) * lda + k0 + (e & 63), &As[buf][e]);
    }
  };
  auto stB = [&](int buf, int k0) {
#pragma unroll
    for (int i = 0; i < RB; ++i) {
      int e = (i * 256 + tid) * 8;
      gload16(Bp + (size_t)(bn + (e >> 6)) * ldb + k0 + (e & 63), &Bs[buf][e]);
    }
  };

  f32x4 acc[FM][FN] = {};
  stA(0, 0); stB(0, 0);
  asm volatile("s_waitcnt vmcnt(0)" ::: "memory");
  __syncthreads();
  int cur = 0;
  for (int k0 = 0; k0 < K; k0 += BK) {
    if (k0 + BK < K) { stA(cur ^ 1, k0 + BK); stB(cur ^ 1, k0 + BK); }
#pragma unroll
    for (int ks = 0; ks < 2; ++ks) {
      const int kx = (ks * 32 + g * 8) ^ sw;
      bf16x8 a[FM], b[FN];
#pragma unroll
      for (int m = 0; m < FM; ++m)
        a[m] = *(const bf16x8*)&As[cur][(wr * WM + m * 16 + lq) * BK + kx];
#pragma unroll
      for (int n = 0; n < FN; ++n)
        b[n] = *(const bf16x8*)&Bs[cur][(wc * WN + n * 16 + lq) * BK + kx];
#pragma unroll
      for (int m = 0; m < FM; ++m)
#pragma unroll
        for (int n = 0; n < FN; ++n)
          acc[m][n] = __builtin_amdgcn_mfma_f32_16x16x32_bf16(a[m], b[n], acc[m][n], 0, 0, 0);
    }
    __syncthreads();
    cur ^= 1;
  }
  // D layout: col = lane&15 (B index), row = (lane>>4)*4 + r (A index)
#pragma unroll
  for (int m = 0; m < FM; ++m) {
    const int rowb = bm + wr * WM + m * 16 + g * 4;
#pragma unroll
    for (int n = 0; n < FN; ++n) {
      const int col = bn + wc * WN + n * 16 + lq;
#pragma unroll
      for (int r = 0; r < 4; ++r) {
        const int row = rowb + r;
        float v = acc[m][n][r];
        if (OUT == 0) {
          ((float*)C0 + z * zsC)[(size_t)row * ldc + col] = v;
        } else if (OUT == 5) {
          ((unsigned short*)C0 + z * zsC)[(size_t)row * ldc + (col ^ ((row & 7) << 3))] = f2bf(v);
        } else {  // OUT == 4
          const int b = row / SL, s = row - b * SL;
          const int which = col >> 8;     // 0=Q,1=K,2=V
          const int ch = col & 255;
          float vp = __shfl_xor(v, 1);    // partner channel (ch^1)
          if (which < 2 && sinT) {
            float sn = sinT[(size_t)s * CH + ch];
            float cs = cosT[(size_t)s * CH + ch];
            v = ((lane & 1) == 0) ? v * cs - vp * sn : v * cs + vp * sn;
          }
          if (which == 0) v *= 0.17677669529663687f;  // 1/sqrt(32) folded into Q
          const int h = ch >> 5, d = ch & 31;
          if (which == 0)
            ((f16*)C0)[(((size_t)b * NHD + h) * SL + s) * DHD + d] = (f16)v;
          else if (which == 1)
            ((f16*)C1)[(((size_t)b * NHD + h) * SL + s) * DHD + d] = (f16)v;
          else
            ((f16*)C2)[(((size_t)b * NHD + h) * DHD + d) * SL + s] = (f16)v;
        }
      }
    }
  }
}

// ---------------- fused flash attention (1-deep register prefetch) ----------------
// qh,kh: f16 [bh][576][32]; vt: f16 [bh][32][576]; msgA: bf16 swizzled [token][256]
__global__ __launch_bounds__(64) void k_attn(const f16* __restrict__ qh,
                                             const f16* __restrict__ kh,
                                             const f16* __restrict__ vt,
                                             unsigned short* __restrict__ msgA) {
  const int bh = blockIdx.x;
  const int b = bh >> 3, h = bh & 7;
  const int lane = threadIdx.x;
  const int lq = lane & 15, g = lane >> 4;
  const int q0 = blockIdx.y * 16;

  const f16x8 qf = *(const f16x8*)&qh[((size_t)bh * SL + q0 + lq) * DHD + g * 8];
  const f16* kbase = kh + (size_t)bh * SL * DHD;
  const f16* vbase = vt + (size_t)bh * DHD * SL;

  f16x8 kf = *(const f16x8*)&kbase[(size_t)lq * DHD + g * 8];
  f16x4 va = *(const f16x4*)&vbase[(size_t)lq * SL + g * 4];
  f16x4 vb = *(const f16x4*)&vbase[(size_t)(16 + lq) * SL + g * 4];

  f32x4 o0 = {}, o1 = {};          // O^T[d][q]
  float m = -1e30f, l = 0.f;
  for (int t = 0; t < 36; ++t) {
    const int tn = t < 35 ? t + 1 : 35;
    f16x8 kfn = *(const f16x8*)&kbase[((size_t)(tn * 16 + lq)) * DHD + g * 8];
    f16x4 van = *(const f16x4*)&vbase[(size_t)lq * SL + tn * 16 + g * 4];
    f16x4 vbn = *(const f16x4*)&vbase[(size_t)(16 + lq) * SL + tn * 16 + g * 4];
    f32x4 s = __builtin_amdgcn_mfma_f32_16x16x32_f16(kf, qf, (f32x4){0.f, 0.f, 0.f, 0.f}, 0, 0, 0);
    float tm = fmaxf(fmaxf(s[0], s[1]), fmaxf(s[2], s[3]));
    tm = fmaxf(tm, __shfl_xor(tm, 16));
    tm = fmaxf(tm, __shfl_xor(tm, 32));
    if (__any(tm > m + 5.f)) {            // deferred-max rescale (THR=5)
      float mn = fmaxf(m, tm);
      float f = __expf(m - mn);
      o0 *= f; o1 *= f; l *= f; m = mn;
    }
    float e0 = __expf(s[0] - m), e1 = __expf(s[1] - m);
    float e2 = __expf(s[2] - m), e3 = __expf(s[3] - m);
    l += (e0 + e1) + (e2 + e3);
    f16x4 ef = {(f16)e0, (f16)e1, (f16)e2, (f16)e3};
    o0 = __builtin_amdgcn_mfma_f32_16x16x16f16(va, ef, o0, 0, 0, 0);
    o1 = __builtin_amdgcn_mfma_f32_16x16x16f16(vb, ef, o1, 0, 0, 0);
    kf = kfn; va = van; vb = vbn;
  }
  l += __shfl_xor(l, 16);
  l += __shfl_xor(l, 32);
  float inv = 1.f / l;
  const int swz = (lq & 7) << 3;            // (token row & 7) = lq & 7
  unsigned short* mrow = msgA + ((size_t)(b * SL + q0 + lq)) * CH;
#pragma unroll
  for (int mt = 0; mt < 2; ++mt) {
    f32x4 o = mt ? o1 : o0;
    unsigned a0 = f2bf(o[0] * inv) | ((unsigned)f2bf(o[1] * inv) << 16);
    unsigned a1 = f2bf(o[2] * inv) | ((unsigned)f2bf(o[3] * inv) << 16);
    uint2 u; u.x = a0; u.y = a1;
    *(uint2*)&mrow[(h * DHD + mt * 16 + g * 4) ^ swz] = u;
  }
}

// ---------------- FFN1: h1 = LeakyReLU(xb @ w1_top + interp(Z)) (pipelined) ----------------
__global__ __launch_bounds__(256) void k_ffn1(const unsigned short* __restrict__ xb,
                                              const unsigned short* __restrict__ w1T,
                                              const float* __restrict__ Z,
                                              unsigned short* __restrict__ h1) {
  constexpr int BM = 128, BN = 128, BK = 64, K = 256;
  constexpr int WM = 64, WN = 64, FM = 4, FN = 4;
  __shared__ unsigned short As[2][BM * BK];
  __shared__ unsigned short Bs[2][BN * BK];
  const int tid = threadIdx.x;
  const int lane = tid & 63, w = tid >> 6;
  const int wr = w >> 1, wc = w & 1;
  const int lq = lane & 15, g = lane >> 4;
  const int sw = (lq & 7) << 3;
  const int bm = blockIdx.x * BM, bn = blockIdx.y * BN;

  auto stA = [&](int buf, int k0) {
#pragma unroll
    for (int i = 0; i < 4; ++i) {
      int e = (i * 256 + tid) * 8;
      gload16(xb + (size_t)(bm + (e >> 6)) * 256 + k0 + (e & 63), &As[buf][e]);
    }
  };
  auto stB = [&](int buf, int k0) {
#pragma unroll
    for (int i = 0; i < 4; ++i) {
      int e = (i * 256 + tid) * 8;
      gload16(w1T + (size_t)(bn + (e >> 6)) * 512 + k0 + (e & 63), &Bs[buf][e]);
    }
  };

  f32x4 acc[FM][FN] = {};
  stA(0, 0); stB(0, 0);
  asm volatile("s_waitcnt vmcnt(0)" ::: "memory");
  __syncthreads();
  int cur = 0;
  for (int k0 = 0; k0 < K; k0 += BK) {
    if (k0 + BK < K) { stA(cur ^ 1, k0 + BK); stB(cur ^ 1, k0 + BK); }
#pragma unroll
    for (int ks = 0; ks < 2; ++ks) {
      const int kx = (ks * 32 + g * 8) ^ sw;
      bf16x8 a[FM], b[FN];
#pragma unroll
      for (int m = 0; m < FM; ++m)
        a[m] = *(const bf16x8*)&As[cur][(wr * WM + m * 16 + lq) * BK + kx];
#pragma unroll
      for (int n = 0; n < FN; ++n)
        b[n] = *(const bf16x8*)&Bs[cur][(wc * WN + n * 16 + lq) * BK + kx];
#pragma unroll
      for (int m = 0; m < FM; ++m)
#pragma unroll
        for (int n = 0; n < FN; ++n)
          acc[m][n] = __builtin_amdgcn_mfma_f32_16x16x32_bf16(a[m], b[n], acc[m][n], 0, 0, 0);
    }
    __syncthreads();
    cur ^= 1;
  }
#pragma unroll
  for (int m = 0; m < FM; ++m) {
    const int rowb = bm + wr * WM + m * 16 + g * 4;
#pragma unroll
    for (int r = 0; r < 4; ++r) {
      const int row = rowb + r;
      const int b = row / PIX;
      const int p = row - b * PIX;
      const int y = p / IW, xx = p - y * IW;
      float sy = (y + 0.5f) * 0.25f - 0.5f;
      float sx = (xx + 0.5f) * 0.25f - 0.5f;
      int y0 = (int)floorf(sy); float wy = sy - y0;
      int x0 = (int)floorf(sx); float wx = sx - x0;
      int y1 = min(y0 + 1, HSS - 1); y0 = max(y0, 0);
      int x1 = min(x0 + 1, WSS - 1); x0 = max(x0, 0);
      const float* Zb = Z + (size_t)b * SL * CH2;
      const float* z00 = Zb + (size_t)(y0 * WSS + x0) * CH2;
      const float* z01 = Zb + (size_t)(y0 * WSS + x1) * CH2;
      const float* z10 = Zb + (size_t)(y1 * WSS + x0) * CH2;
      const float* z11 = Zb + (size_t)(y1 * WSS + x1) * CH2;
      float w00 = (1.f - wy) * (1.f - wx), w01 = (1.f - wy) * wx;
      float w10 = wy * (1.f - wx), w11 = wy * wx;
      const int rs = (row & 7) << 3;
#pragma unroll
      for (int n = 0; n < FN; ++n) {
        const int col = bn + wc * WN + n * 16 + lq;
        float v = acc[m][n][r] + w00 * z00[col] + w01 * z01[col] +
                  w10 * z10[col] + w11 * z11[col];
        v = v >= 0.f ? v : 0.01f * v;
        h1[(size_t)row * CH2 + (col ^ rs)] = f2bf(v);
      }
    }
  }
}

// ---------------- FFN2 + LayerNorm + residual (BM=32, pipelined) ----------------
__global__ __launch_bounds__(256) void k_ffn2(const unsigned short* __restrict__ A,
                                              const unsigned short* __restrict__ Bt,
                                              const float* __restrict__ g2,
                                              const float* __restrict__ b2,
                                              float* __restrict__ x,
                                              unsigned short* __restrict__ xb) {
  constexpr int BM = 32, BK = 64, K = 512;
  __shared__ unsigned short As[2][BM * BK];
  __shared__ unsigned short Bs[2][256 * BK];
  __shared__ float sS[2][BM], sQ[2][BM];
  __shared__ float gS[256], bS[256];
  const int tid = threadIdx.x;
  const int lane = tid & 63, w = tid >> 6;
  const int wr = w >> 1, wc = w & 1;
  const int lq = lane & 15, g = lane >> 4;
  const int sw = (lq & 7) << 3;
  const int bm = blockIdx.x * BM;
  gS[tid] = g2[tid]; bS[tid] = b2[tid];

  auto stA = [&](int buf, int k0) {
    int e = tid * 8;
    gload16(A + (size_t)(bm + (e >> 6)) * K + k0 + (e & 63), &As[buf][e]);
  };
  auto stB = [&](int buf, int k0) {
#pragma unroll
    for (int i = 0; i < 8; ++i) {
      int e = (i * 256 + tid) * 8;
      gload16(Bt + (size_t)(e >> 6) * K + k0 + (e & 63), &Bs[buf][e]);
    }
  };

  f32x4 acc[8] = {};
  stA(0, 0); stB(0, 0);
  asm volatile("s_waitcnt vmcnt(0)" ::: "memory");
  __syncthreads();
  int cur = 0;
  for (int k0 = 0; k0 < K; k0 += BK) {
    if (k0 + BK < K) { stA(cur ^ 1, k0 + BK); stB(cur ^ 1, k0 + BK); }
#pragma unroll
    for (int ks = 0; ks < 2; ++ks) {
      const int kx = (ks * 32 + g * 8) ^ sw;
      bf16x8 a = *(const bf16x8*)&As[cur][(wr * 16 + lq) * BK + kx];
      bf16x8 b[8];
#pragma unroll
      for (int n = 0; n < 8; ++n)
        b[n] = *(const bf16x8*)&Bs[cur][(wc * 128 + n * 16 + lq) * BK + kx];
#pragma unroll
      for (int n = 0; n < 8; ++n)
        acc[n] = __builtin_amdgcn_mfma_f32_16x16x32_bf16(a, b[n], acc[n], 0, 0, 0);
    }
    __syncthreads();
    cur ^= 1;
  }
  // row stats over this wave's 128 cols, combine wc halves
#pragma unroll
  for (int r = 0; r < 4; ++r) {
    float s1 = 0.f, s2 = 0.f;
#pragma unroll
    for (int n = 0; n < 8; ++n) {
      float v = acc[n][r];
      s1 += v; s2 += v * v;
    }
#pragma unroll
    for (int d = 1; d < 16; d <<= 1) {
      s1 += __shfl_xor(s1, d);
      s2 += __shfl_xor(s2, d);
    }
    if (lq == 0) {
      int row = wr * 16 + g * 4 + r;
      sS[wc][row] = s1; sQ[wc][row] = s2;
    }
  }
  __syncthreads();
#pragma unroll
  for (int r = 0; r < 4; ++r) {
    int row = wr * 16 + g * 4 + r;
    float mu = (sS[0][row] + sS[1][row]) * (1.f / CH);
    float var = (sQ[0][row] + sQ[1][row]) * (1.f / CH) - mu * mu;
    float rs = rsqrtf(var + 1e-5f);
    size_t gr = (size_t)(bm + row) * CH;
    const int swr = ((bm + row) & 7) << 3;
#pragma unroll
    for (int n = 0; n < 8; ++n) {
      int col = wc * 128 + n * 16 + lq;
      float o = (acc[n][r] - mu) * rs * gS[col] + bS[col];
      float nx = x[gr + col] + o;
      x[gr + col] = nx;
      xb[gr + (col ^ swr)] = f2bf(nx);
    }
  }
}

// ---------------- host-side orchestration ----------------
struct LayerP {
  const float *aggw, *g1, *b1, *g2, *b2;
  const unsigned short *qkvT, *w1T, *w2T, *wcT;
};

struct Bufs {
  unsigned short *qln, *sln, *msgA, *h1, *xb;
  f16 *qh, *kh, *vt;
  float *Zbuf, *f;
  const float *sinT, *cosT;
};

// attention part: agg + fused QKV proj + flash attn + Z GEMM (merge folded into Wcomb)
static void attn_part(long xoff, long soff, const LayerP& p, bool rope, int nb,
                      const Bufs& B, hipStream_t stream) {
  const int M = nb * SL;
  k_agg<<<dim3(2 * nb * SL), 256, 0, stream>>>(B.xb + xoff, B.xb + soff, p.aggw,
                                               p.g1, p.b1, B.qln, B.sln, nb);
  const float* sT = rope ? B.sinT : nullptr;
  const float* cT = rope ? B.cosT : nullptr;
  k_mm<32, 64, 4><<<dim3(M / 32, 12), 256, 0, stream>>>(
      B.qln, B.sln, p.qkvT, B.qh, B.kh, B.vt, M, CH, CH, CH, 0, 0, 0, sT, cT, 0, 0, 0);
  k_attn<<<dim3(nb * NHD, 36), 64, 0, stream>>>(B.qh, B.kh, B.vt, B.msgA);
  // Z = msgA @ WcombT^T  (Wcomb = mw @ w1_bot; upsample linearity)
  k_mm<64, 64, 0><<<dim3(M / 64, 8), 256, 0, stream>>>(
      B.msgA, nullptr, p.wcT, B.Zbuf, nullptr, nullptr, M, CH, CH, CH, 0, 0, CH2,
      nullptr, nullptr, 0, 0, 0);
}

// FFN for nf features starting at fi (self: fi=0, nf=2 batched; cross: one feature)
static void ffn_part(int fi, int nf, const float* Zs, const LayerP& p, const Bufs& B,
                     hipStream_t stream) {
  const int M = nf * MFFN;
  k_ffn1<<<dim3(M / 128, 4), 256, 0, stream>>>(B.xb + (long)fi * FEATN, p.w1T, Zs, B.h1);
  k_ffn2<<<dim3(M / 32), 256, 0, stream>>>(B.h1, p.w2T, p.g2, p.b2,
                                           B.f + (long)fi * FEATN, B.xb + (long)fi * FEATN);
}

extern "C" void kernel_launch(void* const* d_in, const int* in_sizes, int n_in,
                              void* d_out, int out_size, void* d_ws, size_t ws_size,
                              hipStream_t stream) {
  const float* in_f0 = (const float*)d_in[0];
  const float* in_f1 = (const float*)d_in[1];
  const float* aggw  = (const float*)d_in[2];
  const float* qw    = (const float*)d_in[3];
  const float* kw    = (const float*)d_in[4];
  const float* vw    = (const float*)d_in[5];
  const float* mw    = (const float*)d_in[6];
  const float* w1    = (const float*)d_in[7];
  const float* w2    = (const float*)d_in[8];
  const float* g1    = (const float*)d_in[9];
  const float* b1    = (const float*)d_in[10];
  const float* g2    = (const float*)d_in[11];
  const float* b2    = (const float*)d_in[12];
  (void)in_sizes; (void)n_in; (void)out_size; (void)ws_size;

  // ---- ws layout (~115 MB; ws >= 268 MB) ----
  char* cur = (char*)d_ws;
  auto alloc = [&](size_t bytes) { void* p = cur; cur += (bytes + 255) & ~(size_t)255; return p; };
  float*          f    = (float*)alloc((size_t)2 * FEATN * 4);           // NHWC f32 master
  unsigned short* xb   = (unsigned short*)alloc((size_t)2 * FEATN * 2);  // bf16 mirror (swizzled)
  unsigned short* h1   = (unsigned short*)alloc((size_t)2 * MFFN * CH2 * 2);
  float*          Zbuf = (float*)alloc((size_t)4 * SL * CH2 * 4);
  unsigned short* msgA = (unsigned short*)alloc((size_t)4 * SL * CH * 2);
  unsigned short* qln  = (unsigned short*)alloc((size_t)4 * SL * CH * 2);
  unsigned short* sln  = (unsigned short*)alloc((size_t)4 * SL * CH * 2);
  f16* qh = (f16*)alloc((size_t)4 * NHD * SL * DHD * 2);
  f16* kh = (f16*)alloc((size_t)4 * NHD * SL * DHD * 2);
  f16* vt = (f16*)alloc((size_t)4 * NHD * SL * DHD * 2);
  float* sinT = (float*)alloc((size_t)SL * CH * 4);
  float* cosT = (float*)alloc((size_t)SL * CH * 4);
  unsigned short* qkvT = (unsigned short*)alloc((size_t)8 * 3 * CH * CH * 2);  // [768][256]
  unsigned short* mwB  = (unsigned short*)alloc((size_t)8 * CH * CH * 2);      // [256][256] (mw as-is)
  unsigned short* w1T  = (unsigned short*)alloc((size_t)8 * CH2 * CH2 * 2);    // [512][512]
  unsigned short* w2T  = (unsigned short*)alloc((size_t)8 * CH * CH2 * 2);     // [256][512]
  unsigned short* wcT  = (unsigned short*)alloc((size_t)8 * CH2 * CH * 2);     // [512][256]

  // init: transposes, tables, weight prep
  k_in_tr<<<dim3(PIX / 32, CH / 32, BSZ), 256, 0, stream>>>(in_f0, f, xb);
  k_in_tr<<<dim3(PIX / 32, CH / 32, BSZ), 256, 0, stream>>>(in_f1, f + FEATN, xb + FEATN);
  k_rope_tables<<<dim3(SL), 256, 0, stream>>>(sinT, cosT);
  k_wt<<<dim3(CH / 32, CH / 32, 8), 256, 0, stream>>>(qw, qkvT, CH, CH, (long)CH * CH, (long)3 * CH * CH);
  k_wt<<<dim3(CH / 32, CH / 32, 8), 256, 0, stream>>>(kw, qkvT + (size_t)CH * CH, CH, CH, (long)CH * CH, (long)3 * CH * CH);
  k_wt<<<dim3(CH / 32, CH / 32, 8), 256, 0, stream>>>(vw, qkvT + (size_t)2 * CH * CH, CH, CH, (long)CH * CH, (long)3 * CH * CH);
  k_cvt<<<dim3(CH, 8), 256, 0, stream>>>(mw, mwB);
  k_wt<<<dim3(CH2 / 32, CH2 / 32, 8), 256, 0, stream>>>(w1, w1T, CH2, CH2, (long)CH2 * CH2, (long)CH2 * CH2);
  k_wt<<<dim3(CH / 32, CH2 / 32, 8), 256, 0, stream>>>(w2, w2T, CH2, CH, (long)CH2 * CH, (long)CH * CH2);
  // WcombT[j][i] = sum_k w1T[j][256+k] * mwB[i][k]   (batched over 8 layers)
  k_mm<64, 64, 5><<<dim3(CH2 / 64, CH / 64, 8), 256, 0, stream>>>(
      w1T, nullptr, mwB, wcT, nullptr, nullptr, CH2, CH, CH2, CH, 256, 0, CH,
      nullptr, nullptr, (long)CH2 * CH2, (long)CH * CH, (long)CH2 * CH);

  Bufs B{qln, sln, msgA, h1, xb, qh, kh, vt, Zbuf, f, sinT, cosT};

  for (int i = 0; i < 8; ++i) {
    LayerP p{aggw + (long)i * CH * 16,
             g1 + i * CH, b1 + i * CH, g2 + i * CH, b2 + i * CH,
             qkvT + (long)i * 3 * CH * CH,
             w1T + (long)i * CH2 * CH2, w2T + (long)i * CH * CH2,
             wcT + (long)i * CH2 * CH};
    if ((i & 1) == 0) {
      // self: f0,f1 independent -> batch attention nb=4 and FFN over both features
      attn_part(0, 0, p, true, 4, B, stream);
      ffn_part(0, 2, Zbuf, p, B, stream);
    } else {
      // cross: sequential (feat1's source is the UPDATED feat0)
      attn_part(0, FEATN, p, false, 2, B, stream);
      ffn_part(0, 1, Zbuf, p, B, stream);
      attn_part(FEATN, 0, p, false, 2, B, stream);
      ffn_part(1, 1, Zbuf, p, B, stream);
    }
  }

  // final: NHWC -> NCHW directly into d_out
  float* outp = (float*)d_out;
  k_out_tr<<<dim3(PIX / 32, CH / 32, BSZ), 256, 0, stream>>>(f, outp);
  k_out_tr<<<dim3(PIX / 32, CH / 32, BSZ), 256, 0, stream>>>(f + FEATN, outp + FEATN);
}